// Round 1
// baseline (13496.463 us; speedup 1.0000x reference)
//
#include <hip/hip_runtime.h>
#include <math.h>

// Problem constants
#define Dn   1024
#define Hn   16
#define HDn  64
#define Tn   1024
#define Bn   4
#define Vn   32000
#define Ln   3
#define NT   (Bn*Tn)        // 4096 token rows

// ---------------- embedding: x = tok_emb[idx] + pos_emb[t] ----------------
__global__ __launch_bounds__(256) void embed_kernel(
    const int* __restrict__ idx, const float* __restrict__ tok,
    const float* __restrict__ pos, float* __restrict__ x) {
  int row = blockIdx.x;                 // 0..4095  (b*T + t)
  int t = row & (Tn - 1);
  int token = idx[row];
  const float4* tp = (const float4*)(tok + (size_t)token * Dn);
  const float4* pp = (const float4*)(pos + (size_t)t * Dn);
  float4* xp = (float4*)(x + (size_t)row * Dn);
  int i = threadIdx.x;                  // 256 threads == D/4 float4's
  float4 a = tp[i], b = pp[i];
  xp[i] = make_float4(a.x + b.x, a.y + b.y, a.z + b.z, a.w + b.w);
}

// ---------------- LayerNorm (one block per row, D=1024, 256 threads) -------
__global__ __launch_bounds__(256) void ln_kernel(
    const float* __restrict__ x, const float* __restrict__ g,
    const float* __restrict__ b, float* __restrict__ y) {
  int row = blockIdx.x;
  const float4* xr = (const float4*)(x + (size_t)row * Dn);
  float4* yr = (float4*)(y + (size_t)row * Dn);
  __shared__ float red[4];
  int lane = threadIdx.x & 63, w = threadIdx.x >> 6;

  float4 v = xr[threadIdx.x];
  float s = v.x + v.y + v.z + v.w;
  #pragma unroll
  for (int o = 32; o > 0; o >>= 1) s += __shfl_down(s, o, 64);
  if (lane == 0) red[w] = s;
  __syncthreads();
  float mu = (red[0] + red[1] + red[2] + red[3]) * (1.0f / Dn);
  __syncthreads();

  float dx = v.x - mu, dy = v.y - mu, dz = v.z - mu, dw = v.w - mu;
  float ss = dx*dx + dy*dy + dz*dz + dw*dw;
  #pragma unroll
  for (int o = 32; o > 0; o >>= 1) ss += __shfl_down(ss, o, 64);
  if (lane == 0) red[w] = ss;
  __syncthreads();
  float var = (red[0] + red[1] + red[2] + red[3]) * (1.0f / Dn);
  float inv = rsqrtf(var + 1e-5f);

  float4 gv = ((const float4*)g)[threadIdx.x];
  float4 bv = ((const float4*)b)[threadIdx.x];
  yr[threadIdx.x] = make_float4(dx*inv*gv.x + bv.x, dy*inv*gv.y + bv.y,
                                dz*inv*gv.z + bv.z, dw*inv*gv.w + bv.w);
}

// ---------------- generic fp32 GEMM -----------------------------------
// C[n,m] = sum_k A[n,k] * B(k,m) + bias[m] (+ res[n,m]) (ReLU optional)
// B element address: Bm + k*bsk + (m>>6)*bsh + (m&63)
//   standard [K,M] row-major:   bsk=M,  bsh=64
//   per-head wq[H,D,HD] (m=h*64+e): bsk=64, bsh=D*64
// Tiles 64x64, BK=16, 256 threads, 4x4 microtile. All dims assumed %64/%16.
__global__ __launch_bounds__(256) void gemm_kernel(
    const float* __restrict__ A, const float* __restrict__ Bm,
    const float* __restrict__ bias, const float* __restrict__ res,
    float* __restrict__ C, int N, int K, int M,
    long long bsk, long long bsh, int relu) {
  __shared__ float As[16][68];   // As[kk][n], padded for f4 alignment
  __shared__ float Bs[16][68];   // Bs[kk][m]
  const int n0 = blockIdx.y << 6;
  const int m0 = blockIdx.x << 6;
  const int tid = threadIdx.x;
  const int tx = tid & 15, ty = tid >> 4;

  float acc[4][4] = {{0.f}};

  const int an = tid >> 2;              // 0..63
  const int ak = (tid & 3) << 2;        // 0,4,8,12
  const int bk = tid >> 4;              // 0..15
  const int bm = (tid & 15) << 2;       // 0..60
  const float* Abase = A + (size_t)(n0 + an) * K + ak;
  const float* Bbase = Bm + (size_t)bk * bsk + (size_t)(m0 >> 6) * bsh + bm;

  for (int k0 = 0; k0 < K; k0 += 16) {
    float4 a = *(const float4*)(Abase + k0);
    float4 b = *(const float4*)(Bbase + (size_t)k0 * bsk);
    As[ak + 0][an] = a.x; As[ak + 1][an] = a.y;
    As[ak + 2][an] = a.z; As[ak + 3][an] = a.w;
    *(float4*)&Bs[bk][bm] = b;
    __syncthreads();
    #pragma unroll
    for (int kk = 0; kk < 16; ++kk) {
      float4 a4 = *(const float4*)&As[kk][ty << 2];
      float4 b4 = *(const float4*)&Bs[kk][tx << 2];
      float ar[4] = {a4.x, a4.y, a4.z, a4.w};
      float br[4] = {b4.x, b4.y, b4.z, b4.w};
      #pragma unroll
      for (int i = 0; i < 4; ++i)
        #pragma unroll
        for (int j = 0; j < 4; ++j)
          acc[i][j] = fmaf(ar[i], br[j], acc[i][j]);
    }
    __syncthreads();
  }

  const int mcol = m0 + (tx << 2);
  float4 bz = make_float4(0.f, 0.f, 0.f, 0.f);
  if (bias) bz = *(const float4*)(bias + mcol);
  #pragma unroll
  for (int i = 0; i < 4; ++i) {
    int n = n0 + (ty << 2) + i;
    float4 r = make_float4(acc[i][0] + bz.x, acc[i][1] + bz.y,
                           acc[i][2] + bz.z, acc[i][3] + bz.w);
    if (res) {
      float4 rv = *(const float4*)(res + (size_t)n * M + mcol);
      r.x += rv.x; r.y += rv.y; r.z += rv.z; r.w += rv.w;
    }
    if (relu) {
      r.x = fmaxf(r.x, 0.f); r.y = fmaxf(r.y, 0.f);
      r.z = fmaxf(r.z, 0.f); r.w = fmaxf(r.w, 0.f);
    }
    *(float4*)(C + (size_t)n * M + mcol) = r;
  }
}

// ---------------- attention: one block per (b,h,t) row ---------------------
// q,k,v,o layout: [B*T, D] with D index = h*64+e  (i.e. [B,T,H,HD])
__global__ __launch_bounds__(256) void attn_kernel(
    const float* __restrict__ q, const float* __restrict__ k,
    const float* __restrict__ v, float* __restrict__ o) {
  int bid = blockIdx.x;                   // ((b*H + h) << 10) | t
  int t = bid & (Tn - 1);
  int bh = bid >> 10;
  int b = bh >> 4, h = bh & 15;
  __shared__ float qs[HDn];
  __shared__ float sc[Tn];
  __shared__ float red[4];
  __shared__ float po[4][HDn];

  size_t base = (size_t)b * Tn * Dn + (size_t)h * HDn;  // (b, s=0, h, e=0)
  const float scale = 0.03125f;                          // D^-0.5 = 1/32

  if (threadIdx.x < HDn) qs[threadIdx.x] = q[base + (size_t)t * Dn + threadIdx.x];
  __syncthreads();

  int lane = threadIdx.x & 63, w = threadIdx.x >> 6;
  // scores + running max
  float lmax = -1e30f;
  for (int s = threadIdx.x; s <= t; s += 256) {
    const float* kr = k + base + (size_t)s * Dn;
    float dot = 0.f;
    #pragma unroll
    for (int e = 0; e < HDn; e += 4) {
      float4 kv = *(const float4*)(kr + e);
      dot += qs[e]*kv.x + qs[e+1]*kv.y + qs[e+2]*kv.z + qs[e+3]*kv.w;
    }
    dot *= scale;
    sc[s] = dot;
    lmax = fmaxf(lmax, dot);
  }
  #pragma unroll
  for (int off = 32; off > 0; off >>= 1) lmax = fmaxf(lmax, __shfl_down(lmax, off, 64));
  if (lane == 0) red[w] = lmax;
  __syncthreads();
  float mx = fmaxf(fmaxf(red[0], red[1]), fmaxf(red[2], red[3]));
  __syncthreads();

  // exp + sum
  float lsum = 0.f;
  for (int s = threadIdx.x; s <= t; s += 256) {
    float p = __expf(sc[s] - mx);
    sc[s] = p;
    lsum += p;
  }
  #pragma unroll
  for (int off = 32; off > 0; off >>= 1) lsum += __shfl_down(lsum, off, 64);
  if (lane == 0) red[w] = lsum;
  __syncthreads();
  float rinv = 1.0f / (red[0] + red[1] + red[2] + red[3]);

  // o[d] = sum_s p[s] * v[s][d]; wave g handles s = g, g+4, ...
  int d = threadIdx.x & 63, g = threadIdx.x >> 6;
  float pacc = 0.f;
  for (int s = g; s <= t; s += 4)
    pacc = fmaf(sc[s], v[base + (size_t)s * Dn + d], pacc);
  po[g][d] = pacc;
  __syncthreads();
  if (threadIdx.x < HDn) {
    float r = (po[0][d] + po[1][d] + po[2][d] + po[3][d]) * rinv;
    o[base + (size_t)t * Dn + d] = r;
  }
}

// ---------------- per-row NLL over V=32000 ---------------------------------
__global__ __launch_bounds__(256) void nll_kernel(
    const float* __restrict__ logits, const int* __restrict__ target,
    float* __restrict__ nll) {
  int row = blockIdx.x;
  const float* lr = logits + (size_t)row * Vn;
  const float4* l4 = (const float4*)lr;
  __shared__ float red[4];
  int lane = threadIdx.x & 63, w = threadIdx.x >> 6;

  float lmax = -1e30f;
  for (int i = threadIdx.x; i < Vn / 4; i += 256) {
    float4 v = l4[i];
    lmax = fmaxf(lmax, fmaxf(fmaxf(v.x, v.y), fmaxf(v.z, v.w)));
  }
  #pragma unroll
  for (int off = 32; off > 0; off >>= 1) lmax = fmaxf(lmax, __shfl_down(lmax, off, 64));
  if (lane == 0) red[w] = lmax;
  __syncthreads();
  float mx = fmaxf(fmaxf(red[0], red[1]), fmaxf(red[2], red[3]));
  __syncthreads();

  float lsum = 0.f;
  for (int i = threadIdx.x; i < Vn / 4; i += 256) {
    float4 v = l4[i];
    lsum += __expf(v.x - mx) + __expf(v.y - mx) + __expf(v.z - mx) + __expf(v.w - mx);
  }
  #pragma unroll
  for (int off = 32; off > 0; off >>= 1) lsum += __shfl_down(lsum, off, 64);
  if (lane == 0) red[w] = lsum;
  __syncthreads();
  if (threadIdx.x == 0) {
    float sum = red[0] + red[1] + red[2] + red[3];
    nll[row] = -(lr[target[row]] - mx - logf(sum));
  }
}

__global__ __launch_bounds__(256) void loss_kernel(
    const float* __restrict__ nll, float* __restrict__ out_loss) {
  __shared__ float red[4];
  int lane = threadIdx.x & 63, w = threadIdx.x >> 6;
  float s = 0.f;
  for (int i = threadIdx.x; i < NT; i += 256) s += nll[i];
  #pragma unroll
  for (int off = 32; off > 0; off >>= 1) s += __shfl_down(s, off, 64);
  if (lane == 0) red[w] = s;
  __syncthreads();
  if (threadIdx.x == 0)
    *out_loss = (red[0] + red[1] + red[2] + red[3]) * (1.0f / NT);
}

// ---------------------------------------------------------------------------
static inline void launch_gemm(const float* A, const float* Bm, const float* bias,
                               const float* res, float* C, int N, int K, int M,
                               long long bsk, long long bsh, int relu,
                               hipStream_t s) {
  dim3 g(M >> 6, N >> 6);
  gemm_kernel<<<g, 256, 0, s>>>(A, Bm, bias, res, C, N, K, M, bsk, bsh, relu);
}

extern "C" void kernel_launch(void* const* d_in, const int* in_sizes, int n_in,
                              void* d_out, int out_size, void* d_ws, size_t ws_size,
                              hipStream_t stream) {
  const int*   idx    = (const int*)d_in[0];
  const int*   target = (const int*)d_in[1];
  const float* tok    = (const float*)d_in[2];
  const float* pos    = (const float*)d_in[3];
  const float* wq     = (const float*)d_in[4];
  const float* wk     = (const float*)d_in[5];
  const float* wv     = (const float*)d_in[6];
  const float* wproj  = (const float*)d_in[7];
  const float* bproj  = (const float*)d_in[8];
  const float* ln1g   = (const float*)d_in[9];
  const float* ln1b   = (const float*)d_in[10];
  const float* ln2g   = (const float*)d_in[11];
  const float* ln2b   = (const float*)d_in[12];
  const float* w1     = (const float*)d_in[13];
  const float* b1     = (const float*)d_in[14];
  const float* w2     = (const float*)d_in[15];
  const float* b2     = (const float*)d_in[16];
  const float* lnfg   = (const float*)d_in[17];
  const float* lnfb   = (const float*)d_in[18];
  const float* wlm    = (const float*)d_in[19];
  const float* blm    = (const float*)d_in[20];

  float* out = (float*)d_out;          // logits [4096,32000] + loss scalar

  // workspace layout (floats):
  //   x  : 4096*1024
  //   xn : 4096*1024
  //   reg: 4096*4096  -- shared between {q,k,v,o} (4x 4096*1024) and MLP h
  //   nll: 4096
  float* x    = (float*)d_ws;
  float* xn   = x  + (size_t)NT * Dn;
  float* reg  = xn + (size_t)NT * Dn;
  float* q    = reg;
  float* kbuf = reg + (size_t)NT * Dn;
  float* vbuf = reg + 2 * (size_t)NT * Dn;
  float* obuf = reg + 3 * (size_t)NT * Dn;
  float* hbuf = reg;                              // overlaps q..o (disjoint in time)
  float* nll  = reg + (size_t)NT * 4 * Dn;

  embed_kernel<<<NT, 256, 0, stream>>>(idx, tok, pos, x);

  for (int l = 0; l < Ln; ++l) {
    const float* wq_l = wq + (size_t)l * Hn * Dn * HDn;
    const float* wk_l = wk + (size_t)l * Hn * Dn * HDn;
    const float* wv_l = wv + (size_t)l * Hn * Dn * HDn;

    ln_kernel<<<NT, 256, 0, stream>>>(x, ln1g + l * Dn, ln1b + l * Dn, xn);

    // q/k/v: per-head weights consumed in place (bsk=HD, bsh=D*HD)
    launch_gemm(xn, wq_l, nullptr, nullptr, q,    NT, Dn, Dn, HDn, (long long)Dn * HDn, 0, stream);
    launch_gemm(xn, wk_l, nullptr, nullptr, kbuf, NT, Dn, Dn, HDn, (long long)Dn * HDn, 0, stream);
    launch_gemm(xn, wv_l, nullptr, nullptr, vbuf, NT, Dn, Dn, HDn, (long long)Dn * HDn, 0, stream);

    attn_kernel<<<Bn * Hn * Tn, 256, 0, stream>>>(q, kbuf, vbuf, obuf);

    // x = x + o @ wproj + bproj
    launch_gemm(obuf, wproj + (size_t)l * Dn * Dn, bproj + l * Dn, x, x,
                NT, Dn, Dn, Dn, 64, 0, stream);

    ln_kernel<<<NT, 256, 0, stream>>>(x, ln2g + l * Dn, ln2b + l * Dn, xn);

    // h = relu(xn @ w1 + b1)
    launch_gemm(xn, w1 + (size_t)l * Dn * 4 * Dn, b1 + l * 4 * Dn, nullptr, hbuf,
                NT, Dn, 4 * Dn, 4 * Dn, 64, 1, stream);
    // x = x + h @ w2 + b2
    launch_gemm(hbuf, w2 + (size_t)l * 4 * Dn * Dn, b2 + l * Dn, x, x,
                NT, 4 * Dn, Dn, Dn, 64, 0, stream);
  }

  ln_kernel<<<NT, 256, 0, stream>>>(x, lnfg, lnfb, xn);

  // logits = xn @ wlm + blm  -> straight into d_out
  launch_gemm(xn, wlm, blm, nullptr, out, NT, Dn, Vn, Vn, 64, 0, stream);

  nll_kernel<<<NT, 256, 0, stream>>>(out, target, nll);
  loss_kernel<<<1, 256, 0, stream>>>(nll, out + (size_t)NT * Vn);
}

// Round 2
// 5661.837 us; speedup vs baseline: 2.3838x; 2.3838x over previous
//
#include <hip/hip_runtime.h>
#include <math.h>

// Problem constants
#define Dn   1024
#define Hn   16
#define HDn  64
#define Tn   1024
#define Bn   4
#define Vn   32000
#define Ln   3
#define NT   (Bn*Tn)        // 4096 token rows

typedef __attribute__((ext_vector_type(8))) short bf16x8;
typedef __attribute__((ext_vector_type(4))) float f32x4;
typedef __attribute__((ext_vector_type(8))) unsigned short u16x8;

__device__ __forceinline__ float b2f(unsigned short u) {
  union { float f; unsigned int i; } c; c.i = ((unsigned int)u) << 16; return c.f;
}
__device__ __forceinline__ unsigned short f2b(float f) {
  union { float f; unsigned int i; } c; c.f = f;
  unsigned int r = (c.i + 0x7FFFu + ((c.i >> 16) & 1u)) >> 16;
  return (unsigned short)r;
}

#define GLOAD_LDS16(g, l) __builtin_amdgcn_global_load_lds( \
    (const __attribute__((address_space(1))) void*)(g),     \
    (__attribute__((address_space(3))) void*)(l), 16, 0, 0)

// ---------------- embedding: x = tok_emb[idx] + pos_emb[t] (fp32) ----------
__global__ __launch_bounds__(256) void embed_kernel(
    const int* __restrict__ idx, const float* __restrict__ tok,
    const float* __restrict__ pos, float* __restrict__ x) {
  int row = blockIdx.x;
  int t = row & (Tn - 1);
  int token = idx[row];
  const float4* tp = (const float4*)(tok + (size_t)token * Dn);
  const float4* pp = (const float4*)(pos + (size_t)t * Dn);
  float4* xp = (float4*)(x + (size_t)row * Dn);
  int i = threadIdx.x;
  float4 a = tp[i], b = pp[i];
  xp[i] = make_float4(a.x + b.x, a.y + b.y, a.z + b.z, a.w + b.w);
}

// ---------------- LayerNorm: fp32 in, bf16 out -----------------------------
__global__ __launch_bounds__(256) void ln_kernel(
    const float* __restrict__ x, const float* __restrict__ g,
    const float* __restrict__ b, unsigned short* __restrict__ y) {
  int row = blockIdx.x;
  const float4* xr = (const float4*)(x + (size_t)row * Dn);
  __shared__ float red[4];
  int lane = threadIdx.x & 63, w = threadIdx.x >> 6;

  float4 v = xr[threadIdx.x];
  float s = v.x + v.y + v.z + v.w;
  #pragma unroll
  for (int o = 32; o > 0; o >>= 1) s += __shfl_down(s, o, 64);
  if (lane == 0) red[w] = s;
  __syncthreads();
  float mu = (red[0] + red[1] + red[2] + red[3]) * (1.0f / Dn);
  __syncthreads();

  float dx = v.x - mu, dy = v.y - mu, dz = v.z - mu, dw = v.w - mu;
  float ss = dx*dx + dy*dy + dz*dz + dw*dw;
  #pragma unroll
  for (int o = 32; o > 0; o >>= 1) ss += __shfl_down(ss, o, 64);
  if (lane == 0) red[w] = ss;
  __syncthreads();
  float var = (red[0] + red[1] + red[2] + red[3]) * (1.0f / Dn);
  float inv = rsqrtf(var + 1e-5f);

  float4 gv = ((const float4*)g)[threadIdx.x];
  float4 bv = ((const float4*)b)[threadIdx.x];
  ushort4 o4;
  o4.x = f2b(dx*inv*gv.x + bv.x);
  o4.y = f2b(dy*inv*gv.y + bv.y);
  o4.z = f2b(dz*inv*gv.z + bv.z);
  o4.w = f2b(dw*inv*gv.w + bv.w);
  ((ushort4*)(y + (size_t)row * Dn))[threadIdx.x] = o4;
}

// ---------------- weight transpose-cast: fp32 B(k,m) -> bf16 BT[m][k] ------
// src element address: src[k*bsk + (m>>6)*bsh + (m&63)]
__global__ __launch_bounds__(256) void wcast_kernel(
    const float* __restrict__ src, unsigned short* __restrict__ dst,
    int K, int M, long long bsk, long long bsh) {
  __shared__ float t[32][33];
  int m0 = blockIdx.x << 5, k0 = blockIdx.y << 5;
  int tid = threadIdx.x;
  int ml = tid & 31, kl = tid >> 5;          // read: coalesced along m
  #pragma unroll
  for (int p = 0; p < 4; ++p) {
    int k = k0 + kl + p * 8;
    int m = m0 + ml;
    t[ml][kl + p * 8] = src[(size_t)k * bsk + (size_t)(m >> 6) * bsh + (m & 63)];
  }
  __syncthreads();
  int kl2 = tid & 31, ml2 = tid >> 5;        // write: coalesced along k
  #pragma unroll
  for (int p = 0; p < 4; ++p) {
    int m = m0 + ml2 + p * 8;
    int k = k0 + kl2;
    dst[(size_t)m * K + k] = f2b(t[ml2 + p * 8][kl2]);
  }
}

// ---------------- bf16 MFMA GEMM (m97 structure, 128x128x32) ---------------
// C[n,m] = sum_k A[n,k]*BT[m,k] (+bias[m]) (+res[n,m]) (relu?)
// A bf16 [N][K], BT bf16 [M][K]. Output either fp32 Cf or bf16 Ch.
__global__ __launch_bounds__(256) void mm_bf16(
    const unsigned short* __restrict__ A, const unsigned short* __restrict__ BT,
    const float* __restrict__ bias, const float* __restrict__ res,
    float* __restrict__ Cf, unsigned short* __restrict__ Ch,
    int N, int K, int M, int relu) {
  __shared__ __align__(16) unsigned short As[128 * 32];
  __shared__ __align__(16) unsigned short Bs[128 * 32];
  const int tid = threadIdx.x;
  const int lane = tid & 63, w = tid >> 6;
  const int wr = w >> 1, wc = w & 1;
  const int n0 = blockIdx.y << 7, m0 = blockIdx.x << 7;

  f32x4 acc[4][4];
  #pragma unroll
  for (int i = 0; i < 4; ++i)
    #pragma unroll
    for (int j = 0; j < 4; ++j)
      acc[i][j] = (f32x4){0.f, 0.f, 0.f, 0.f};

  // staging source addresses (inverse-swizzled global, linear LDS dest)
  // chunk i of wave w: LDS bytes [w*2048 + i*1024, +1024)
  const int beta0 = w * 2048 + lane * 16;
  const int beta1 = beta0 + 1024;
  const int r0 = beta0 >> 6, u0 = (beta0 >> 4) & 3;
  const int r1 = beta1 >> 6, u1 = (beta1 >> 4) & 3;
  const int ks0 = u0 ^ ((r0 >> 1) & 3);
  const int ks1 = u1 ^ ((r1 >> 1) & 3);
  const unsigned short* a_g0 = A + (size_t)(n0 + r0) * K + ks0 * 8;
  const unsigned short* a_g1 = A + (size_t)(n0 + r1) * K + ks1 * 8;
  const unsigned short* b_g0 = BT + (size_t)(m0 + r0) * K + ks0 * 8;
  const unsigned short* b_g1 = BT + (size_t)(m0 + r1) * K + ks1 * 8;
  unsigned short* a_l0 = As + w * 1024;
  unsigned short* a_l1 = As + w * 1024 + 512;
  unsigned short* b_l0 = Bs + w * 1024;
  unsigned short* b_l1 = Bs + w * 1024 + 512;

  // fragment read byte offsets (swizzled)
  int a_off[4], b_off[4];
  #pragma unroll
  for (int f = 0; f < 4; ++f) {
    int row = wr * 64 + f * 16 + (lane & 15);
    a_off[f] = row * 64 + (((lane >> 4) ^ ((row >> 1) & 3)) << 4);
    int col = wc * 64 + f * 16 + (lane & 15);
    b_off[f] = col * 64 + (((lane >> 4) ^ ((col >> 1) & 3)) << 4);
  }

  for (int k0 = 0; k0 < K; k0 += 32) {
    __syncthreads();
    GLOAD_LDS16(a_g0 + k0, a_l0);
    GLOAD_LDS16(a_g1 + k0, a_l1);
    GLOAD_LDS16(b_g0 + k0, b_l0);
    GLOAD_LDS16(b_g1 + k0, b_l1);
    __syncthreads();

    bf16x8 af[4], bfr[4];
    #pragma unroll
    for (int f = 0; f < 4; ++f) {
      af[f]  = *(const bf16x8*)((const char*)As + a_off[f]);
      bfr[f] = *(const bf16x8*)((const char*)Bs + b_off[f]);
    }
    #pragma unroll
    for (int i = 0; i < 4; ++i)
      #pragma unroll
      for (int j = 0; j < 4; ++j)
        acc[i][j] = __builtin_amdgcn_mfma_f32_16x16x32_bf16(af[i], bfr[j], acc[i][j], 0, 0, 0);
  }

  // epilogue: D[row=(lane>>4)*4+i][col=lane&15] per fragment
  #pragma unroll
  for (int fc = 0; fc < 4; ++fc) {
    int colg = m0 + wc * 64 + fc * 16 + (lane & 15);
    float bz = bias ? bias[colg] : 0.f;
    #pragma unroll
    for (int fr = 0; fr < 4; ++fr) {
      #pragma unroll
      for (int i = 0; i < 4; ++i) {
        int rowg = n0 + wr * 64 + fr * 16 + ((lane >> 4) << 2) + i;
        float v = acc[fr][fc][i] + bz;
        if (res) v += res[(size_t)rowg * M + colg];
        if (relu) v = fmaxf(v, 0.f);
        if (Cf) Cf[(size_t)rowg * M + colg] = v;
        else    Ch[(size_t)rowg * M + colg] = f2b(v);
      }
    }
  }
}

// ---------------- attention: one block per (b,h,t) row, bf16 in/out --------
__global__ __launch_bounds__(256) void attn_kernel(
    const unsigned short* __restrict__ q, const unsigned short* __restrict__ k,
    const unsigned short* __restrict__ v, unsigned short* __restrict__ o) {
  int bid = blockIdx.x;                   // ((b*H + h) << 10) | t
  int t = bid & (Tn - 1);
  int bh = bid >> 10;
  int b = bh >> 4, h = bh & 15;
  __shared__ float qs[HDn];
  __shared__ float sc[Tn];
  __shared__ float red[4];
  __shared__ float po[4][HDn];

  size_t base = (size_t)b * Tn * Dn + (size_t)h * HDn;
  const float scale = 0.03125f;           // D^-0.5

  if (threadIdx.x < HDn) qs[threadIdx.x] = b2f(q[base + (size_t)t * Dn + threadIdx.x]);
  __syncthreads();

  int lane = threadIdx.x & 63, w = threadIdx.x >> 6;
  float lmax = -1e30f;
  for (int s = threadIdx.x; s <= t; s += 256) {
    const u16x8* kr = (const u16x8*)(k + base + (size_t)s * Dn);
    float dot = 0.f;
    #pragma unroll
    for (int eb = 0; eb < 8; ++eb) {
      u16x8 kv = kr[eb];
      #pragma unroll
      for (int j = 0; j < 8; ++j) dot = fmaf(qs[eb * 8 + j], b2f(kv[j]), dot);
    }
    dot *= scale;
    sc[s] = dot;
    lmax = fmaxf(lmax, dot);
  }
  #pragma unroll
  for (int off = 32; off > 0; off >>= 1) lmax = fmaxf(lmax, __shfl_down(lmax, off, 64));
  if (lane == 0) red[w] = lmax;
  __syncthreads();
  float mx = fmaxf(fmaxf(red[0], red[1]), fmaxf(red[2], red[3]));
  __syncthreads();

  float lsum = 0.f;
  for (int s = threadIdx.x; s <= t; s += 256) {
    float p = __expf(sc[s] - mx);
    sc[s] = p;
    lsum += p;
  }
  #pragma unroll
  for (int off = 32; off > 0; off >>= 1) lsum += __shfl_down(lsum, off, 64);
  if (lane == 0) red[w] = lsum;
  __syncthreads();
  float rinv = 1.0f / (red[0] + red[1] + red[2] + red[3]);

  int d = threadIdx.x & 63, g = threadIdx.x >> 6;
  float pacc = 0.f;
  for (int s = g; s <= t; s += 4)
    pacc = fmaf(sc[s], b2f(v[base + (size_t)s * Dn + d]), pacc);
  po[g][d] = pacc;
  __syncthreads();
  if (threadIdx.x < HDn) {
    float r = (po[0][d] + po[1][d] + po[2][d] + po[3][d]) * rinv;
    o[base + (size_t)t * Dn + d] = f2b(r);
  }
}

// ---------------- per-row NLL over V=32000 (fp32 logits) -------------------
__global__ __launch_bounds__(256) void nll_kernel(
    const float* __restrict__ logits, const int* __restrict__ target,
    float* __restrict__ nll) {
  int row = blockIdx.x;
  const float* lr = logits + (size_t)row * Vn;
  const float4* l4 = (const float4*)lr;
  __shared__ float red[4];
  int lane = threadIdx.x & 63, w = threadIdx.x >> 6;

  float lmax = -1e30f;
  for (int i = threadIdx.x; i < Vn / 4; i += 256) {
    float4 v = l4[i];
    lmax = fmaxf(lmax, fmaxf(fmaxf(v.x, v.y), fmaxf(v.z, v.w)));
  }
  #pragma unroll
  for (int off = 32; off > 0; off >>= 1) lmax = fmaxf(lmax, __shfl_down(lmax, off, 64));
  if (lane == 0) red[w] = lmax;
  __syncthreads();
  float mx = fmaxf(fmaxf(red[0], red[1]), fmaxf(red[2], red[3]));
  __syncthreads();

  float lsum = 0.f;
  for (int i = threadIdx.x; i < Vn / 4; i += 256) {
    float4 v = l4[i];
    lsum += __expf(v.x - mx) + __expf(v.y - mx) + __expf(v.z - mx) + __expf(v.w - mx);
  }
  #pragma unroll
  for (int off = 32; off > 0; off >>= 1) lsum += __shfl_down(lsum, off, 64);
  if (lane == 0) red[w] = lsum;
  __syncthreads();
  if (threadIdx.x == 0) {
    float sum = red[0] + red[1] + red[2] + red[3];
    nll[row] = -(lr[target[row]] - mx - logf(sum));
  }
}

__global__ __launch_bounds__(256) void loss_kernel(
    const float* __restrict__ nll, float* __restrict__ out_loss) {
  __shared__ float red[4];
  int lane = threadIdx.x & 63, w = threadIdx.x >> 6;
  float s = 0.f;
  for (int i = threadIdx.x; i < NT; i += 256) s += nll[i];
  #pragma unroll
  for (int off = 32; off > 0; off >>= 1) s += __shfl_down(s, off, 64);
  if (lane == 0) red[w] = s;
  __syncthreads();
  if (threadIdx.x == 0)
    *out_loss = (red[0] + red[1] + red[2] + red[3]) * (1.0f / NT);
}

// ---------------------------------------------------------------------------
static inline void launch_wcast(const float* src, unsigned short* dst, int K, int M,
                                long long bsk, long long bsh, hipStream_t s) {
  dim3 g(M >> 5, K >> 5);
  wcast_kernel<<<g, 256, 0, s>>>(src, dst, K, M, bsk, bsh);
}

static inline void launch_mm(const unsigned short* A, const unsigned short* BT,
                             const float* bias, const float* res,
                             float* Cf, unsigned short* Ch,
                             int N, int K, int M, int relu, hipStream_t s) {
  dim3 g(M >> 7, N >> 7);
  mm_bf16<<<g, 256, 0, s>>>(A, BT, bias, res, Cf, Ch, N, K, M, relu);
}

extern "C" void kernel_launch(void* const* d_in, const int* in_sizes, int n_in,
                              void* d_out, int out_size, void* d_ws, size_t ws_size,
                              hipStream_t stream) {
  const int*   idx    = (const int*)d_in[0];
  const int*   target = (const int*)d_in[1];
  const float* tok    = (const float*)d_in[2];
  const float* pos    = (const float*)d_in[3];
  const float* wq     = (const float*)d_in[4];
  const float* wk     = (const float*)d_in[5];
  const float* wv     = (const float*)d_in[6];
  const float* wproj  = (const float*)d_in[7];
  const float* bproj  = (const float*)d_in[8];
  const float* ln1g   = (const float*)d_in[9];
  const float* ln1b   = (const float*)d_in[10];
  const float* ln2g   = (const float*)d_in[11];
  const float* ln2b   = (const float*)d_in[12];
  const float* w1     = (const float*)d_in[13];
  const float* b1     = (const float*)d_in[14];
  const float* w2     = (const float*)d_in[15];
  const float* b2     = (const float*)d_in[16];
  const float* lnfg   = (const float*)d_in[17];
  const float* lnfb   = (const float*)d_in[18];
  const float* wlm    = (const float*)d_in[19];
  const float* blm    = (const float*)d_in[20];

  float* out = (float*)d_out;          // logits [4096,32000] + loss scalar

  // workspace layout:
  //   x   fp32  NT*D               16.8 MB
  //   xn  bf16  NT*D                8.4 MB
  //   reg bf16  NT*4D   {q|k|v|o} or {h}   33.6 MB
  //   wT  bf16  V*D (max weight)   65.6 MB
  //   nll fp32  NT
  char* p = (char*)d_ws;
  float* x  = (float*)p;                 p += (size_t)NT * Dn * 4;
  unsigned short* xn = (unsigned short*)p; p += (size_t)NT * Dn * 2;
  unsigned short* reg = (unsigned short*)p; p += (size_t)NT * 4 * Dn * 2;
  unsigned short* wT = (unsigned short*)p; p += (size_t)Vn * Dn * 2;
  float* nll = (float*)p;

  unsigned short* qb = reg;
  unsigned short* kb = reg + (size_t)NT * Dn;
  unsigned short* vb = reg + 2 * (size_t)NT * Dn;
  unsigned short* ob = reg + 3 * (size_t)NT * Dn;
  unsigned short* hb = reg;              // overlaps q..o (disjoint in time)

  embed_kernel<<<NT, 256, 0, stream>>>(idx, tok, pos, x);

  for (int l = 0; l < Ln; ++l) {
    const float* wq_l = wq + (size_t)l * Hn * Dn * HDn;
    const float* wk_l = wk + (size_t)l * Hn * Dn * HDn;
    const float* wv_l = wv + (size_t)l * Hn * Dn * HDn;

    ln_kernel<<<NT, 256, 0, stream>>>(x, ln1g + l * Dn, ln1b + l * Dn, xn);

    // per-head wq[h][k][e]: m=h*64+e -> bsk=64, bsh=D*64
    launch_wcast(wq_l, wT, Dn, Dn, HDn, (long long)Dn * HDn, stream);
    launch_mm(xn, wT, nullptr, nullptr, nullptr, qb, NT, Dn, Dn, 0, stream);
    launch_wcast(wk_l, wT, Dn, Dn, HDn, (long long)Dn * HDn, stream);
    launch_mm(xn, wT, nullptr, nullptr, nullptr, kb, NT, Dn, Dn, 0, stream);
    launch_wcast(wv_l, wT, Dn, Dn, HDn, (long long)Dn * HDn, stream);
    launch_mm(xn, wT, nullptr, nullptr, nullptr, vb, NT, Dn, Dn, 0, stream);

    attn_kernel<<<Bn * Hn * Tn, 256, 0, stream>>>(qb, kb, vb, ob);

    // x = x + o @ wproj + bproj    (wproj [K=D][M=D] row-major: bsk=M, bsh=64)
    launch_wcast(wproj + (size_t)l * Dn * Dn, wT, Dn, Dn, Dn, 64, stream);
    launch_mm(ob, wT, bproj + l * Dn, x, x, nullptr, NT, Dn, Dn, 0, stream);

    ln_kernel<<<NT, 256, 0, stream>>>(x, ln2g + l * Dn, ln2b + l * Dn, xn);

    // h = relu(xn @ w1 + b1)
    launch_wcast(w1 + (size_t)l * Dn * 4 * Dn, wT, Dn, 4 * Dn, 4 * Dn, 64, stream);
    launch_mm(xn, wT, b1 + l * 4 * Dn, nullptr, nullptr, hb, NT, Dn, 4 * Dn, 1, stream);
    // x = x + h @ w2 + b2
    launch_wcast(w2 + (size_t)l * 4 * Dn * Dn, wT, 4 * Dn, Dn, Dn, 64, stream);
    launch_mm(hb, wT, b2 + l * Dn, x, x, nullptr, NT, 4 * Dn, Dn, 0, stream);
  }

  ln_kernel<<<NT, 256, 0, stream>>>(x, lnfg, lnfb, xn);

  // logits = xn @ wlm + blm -> d_out (fp32)
  launch_wcast(wlm, wT, Dn, Vn, Vn, 64, stream);
  launch_mm(xn, wT, blm, nullptr, out, nullptr, NT, Dn, Vn, 0, stream);

  nll_kernel<<<NT, 256, 0, stream>>>(out, target, nll);
  loss_kernel<<<1, 256, 0, stream>>>(nll, out + (size_t)NT * Vn);
}

// Round 3
// 1840.978 us; speedup vs baseline: 7.3311x; 3.0755x over previous
//
#include <hip/hip_runtime.h>
#include <math.h>

// Problem constants
#define Dn   1024
#define Hn   16
#define HDn  64
#define Tn   1024
#define Bn   4
#define Vn   32000
#define Ln   3
#define NT   (Bn*Tn)        // 4096 token rows

typedef __attribute__((ext_vector_type(8))) short bf16x8;
typedef __attribute__((ext_vector_type(4))) float f32x4;
typedef __attribute__((ext_vector_type(8))) unsigned short u16x8;

__device__ __forceinline__ float b2f(unsigned short u) {
  union { float f; unsigned int i; } c; c.i = ((unsigned int)u) << 16; return c.f;
}
__device__ __forceinline__ unsigned short f2b(float f) {
  union { float f; unsigned int i; } c; c.f = f;
  unsigned int r = (c.i + 0x7FFFu + ((c.i >> 16) & 1u)) >> 16;
  return (unsigned short)r;
}

#define GLOAD_LDS16(g, l) __builtin_amdgcn_global_load_lds( \
    (const __attribute__((address_space(1))) void*)(g),     \
    (__attribute__((address_space(3))) void*)(l), 16, 0, 0)

// ---------------- embedding: x = tok_emb[idx] + pos_emb[t] (fp32) ----------
__global__ __launch_bounds__(256) void embed_kernel(
    const int* __restrict__ idx, const float* __restrict__ tok,
    const float* __restrict__ pos, float* __restrict__ x) {
  int row = blockIdx.x;
  int t = row & (Tn - 1);
  int token = idx[row];
  const float4* tp = (const float4*)(tok + (size_t)token * Dn);
  const float4* pp = (const float4*)(pos + (size_t)t * Dn);
  float4* xp = (float4*)(x + (size_t)row * Dn);
  int i = threadIdx.x;
  float4 a = tp[i], b = pp[i];
  xp[i] = make_float4(a.x + b.x, a.y + b.y, a.z + b.z, a.w + b.w);
}

// ---------------- LayerNorm: fp32 in, bf16 out -----------------------------
__global__ __launch_bounds__(256) void ln_kernel(
    const float* __restrict__ x, const float* __restrict__ g,
    const float* __restrict__ b, unsigned short* __restrict__ y) {
  int row = blockIdx.x;
  const float4* xr = (const float4*)(x + (size_t)row * Dn);
  __shared__ float red[4];
  int lane = threadIdx.x & 63, w = threadIdx.x >> 6;

  float4 v = xr[threadIdx.x];
  float s = v.x + v.y + v.z + v.w;
  #pragma unroll
  for (int o = 32; o > 0; o >>= 1) s += __shfl_down(s, o, 64);
  if (lane == 0) red[w] = s;
  __syncthreads();
  float mu = (red[0] + red[1] + red[2] + red[3]) * (1.0f / Dn);
  __syncthreads();

  float dx = v.x - mu, dy = v.y - mu, dz = v.z - mu, dw = v.w - mu;
  float ss = dx*dx + dy*dy + dz*dz + dw*dw;
  #pragma unroll
  for (int o = 32; o > 0; o >>= 1) ss += __shfl_down(ss, o, 64);
  if (lane == 0) red[w] = ss;
  __syncthreads();
  float var = (red[0] + red[1] + red[2] + red[3]) * (1.0f / Dn);
  float inv = rsqrtf(var + 1e-5f);

  float4 gv = ((const float4*)g)[threadIdx.x];
  float4 bv = ((const float4*)b)[threadIdx.x];
  ushort4 o4;
  o4.x = f2b(dx*inv*gv.x + bv.x);
  o4.y = f2b(dy*inv*gv.y + bv.y);
  o4.z = f2b(dz*inv*gv.z + bv.z);
  o4.w = f2b(dw*inv*gv.w + bv.w);
  ((ushort4*)(y + (size_t)row * Dn))[threadIdx.x] = o4;
}

// ---------------- weight transpose-cast: fp32 B(k,m) -> bf16 BT[m][k] ------
__global__ __launch_bounds__(256) void wcast_kernel(
    const float* __restrict__ src, unsigned short* __restrict__ dst,
    int K, int M, long long bsk, long long bsh) {
  __shared__ float t[32][33];
  int m0 = blockIdx.x << 5, k0 = blockIdx.y << 5;
  int tid = threadIdx.x;
  int ml = tid & 31, kl = tid >> 5;
  #pragma unroll
  for (int p = 0; p < 4; ++p) {
    int k = k0 + kl + p * 8;
    int m = m0 + ml;
    t[ml][kl + p * 8] = src[(size_t)k * bsk + (size_t)(m >> 6) * bsh + (m & 63)];
  }
  __syncthreads();
  int kl2 = tid & 31, ml2 = tid >> 5;
  #pragma unroll
  for (int p = 0; p < 4; ++p) {
    int m = m0 + ml2 + p * 8;
    int k = k0 + kl2;
    dst[(size_t)m * K + k] = f2b(t[ml2 + p * 8][kl2]);
  }
}

// ---------------- bf16 MFMA GEMM (m97 structure, 128x128x32) ---------------
// omode 0: row-major out (Cf fp32 or Ch bf16), bias/res/relu supported
// omode 1: Ch = QK layout [B][H][T][64]   (rowg=b*T+t, colg=h*64+e)
// omode 2: Ch = Vt layout [B][H][64][T]
__global__ __launch_bounds__(256) void mm_bf16(
    const unsigned short* __restrict__ A, const unsigned short* __restrict__ BT,
    const float* __restrict__ bias, const float* __restrict__ res,
    float* __restrict__ Cf, unsigned short* __restrict__ Ch,
    int N, int K, int M, int relu, int omode) {
  __shared__ __align__(16) unsigned short As[128 * 32];
  __shared__ __align__(16) unsigned short Bs[128 * 32];
  const int tid = threadIdx.x;
  const int lane = tid & 63, w = tid >> 6;
  const int wr = w >> 1, wc = w & 1;
  const int n0 = blockIdx.y << 7, m0 = blockIdx.x << 7;

  f32x4 acc[4][4];
  #pragma unroll
  for (int i = 0; i < 4; ++i)
    #pragma unroll
    for (int j = 0; j < 4; ++j)
      acc[i][j] = (f32x4){0.f, 0.f, 0.f, 0.f};

  const int beta0 = w * 2048 + lane * 16;
  const int beta1 = beta0 + 1024;
  const int r0 = beta0 >> 6, u0 = (beta0 >> 4) & 3;
  const int r1 = beta1 >> 6, u1 = (beta1 >> 4) & 3;
  const int ks0 = u0 ^ ((r0 >> 1) & 3);
  const int ks1 = u1 ^ ((r1 >> 1) & 3);
  const unsigned short* a_g0 = A + (size_t)(n0 + r0) * K + ks0 * 8;
  const unsigned short* a_g1 = A + (size_t)(n0 + r1) * K + ks1 * 8;
  const unsigned short* b_g0 = BT + (size_t)(m0 + r0) * K + ks0 * 8;
  const unsigned short* b_g1 = BT + (size_t)(m0 + r1) * K + ks1 * 8;
  unsigned short* a_l0 = As + w * 1024;
  unsigned short* a_l1 = As + w * 1024 + 512;
  unsigned short* b_l0 = Bs + w * 1024;
  unsigned short* b_l1 = Bs + w * 1024 + 512;

  int a_off[4], b_off[4];
  #pragma unroll
  for (int f = 0; f < 4; ++f) {
    int row = wr * 64 + f * 16 + (lane & 15);
    a_off[f] = row * 64 + (((lane >> 4) ^ ((row >> 1) & 3)) << 4);
    int col = wc * 64 + f * 16 + (lane & 15);
    b_off[f] = col * 64 + (((lane >> 4) ^ ((col >> 1) & 3)) << 4);
  }

  for (int k0 = 0; k0 < K; k0 += 32) {
    __syncthreads();
    GLOAD_LDS16(a_g0 + k0, a_l0);
    GLOAD_LDS16(a_g1 + k0, a_l1);
    GLOAD_LDS16(b_g0 + k0, b_l0);
    GLOAD_LDS16(b_g1 + k0, b_l1);
    __syncthreads();

    bf16x8 af[4], bfr[4];
    #pragma unroll
    for (int f = 0; f < 4; ++f) {
      af[f]  = *(const bf16x8*)((const char*)As + a_off[f]);
      bfr[f] = *(const bf16x8*)((const char*)Bs + b_off[f]);
    }
    #pragma unroll
    for (int i = 0; i < 4; ++i)
      #pragma unroll
      for (int j = 0; j < 4; ++j)
        acc[i][j] = __builtin_amdgcn_mfma_f32_16x16x32_bf16(af[i], bfr[j], acc[i][j], 0, 0, 0);
  }

  if (omode == 0) {
    #pragma unroll
    for (int fc = 0; fc < 4; ++fc) {
      int colg = m0 + wc * 64 + fc * 16 + (lane & 15);
      float bz = bias ? bias[colg] : 0.f;
      #pragma unroll
      for (int fr = 0; fr < 4; ++fr) {
        #pragma unroll
        for (int i = 0; i < 4; ++i) {
          int rowg = n0 + wr * 64 + fr * 16 + ((lane >> 4) << 2) + i;
          float v = acc[fr][fc][i] + bz;
          if (res) v += res[(size_t)rowg * M + colg];
          if (relu) v = fmaxf(v, 0.f);
          if (Cf) Cf[(size_t)rowg * M + colg] = v;
          else    Ch[(size_t)rowg * M + colg] = f2b(v);
        }
      }
    }
  } else if (omode == 1) {
    // Q/K layout: ((b*16+h)*1024 + t)*64 + e
    #pragma unroll
    for (int fc = 0; fc < 4; ++fc) {
      int colg = m0 + wc * 64 + fc * 16 + (lane & 15);
      int h = colg >> 6, e = colg & 63;
      #pragma unroll
      for (int fr = 0; fr < 4; ++fr) {
        #pragma unroll
        for (int i = 0; i < 4; ++i) {
          int rowg = n0 + wr * 64 + fr * 16 + ((lane >> 4) << 2) + i;
          int b = rowg >> 10, t = rowg & 1023;
          Ch[(((size_t)(b * 16 + h) * 1024) + t) * 64 + e] = f2b(acc[fr][fc][i]);
        }
      }
    }
  } else {
    // Vt layout: ((b*16+h)*64 + e)*1024 + t ; 4 consecutive t -> ushort4
    #pragma unroll
    for (int fc = 0; fc < 4; ++fc) {
      int colg = m0 + wc * 64 + fc * 16 + (lane & 15);
      int h = colg >> 6, e = colg & 63;
      #pragma unroll
      for (int fr = 0; fr < 4; ++fr) {
        int rowg0 = n0 + wr * 64 + fr * 16 + ((lane >> 4) << 2);
        int b = rowg0 >> 10, t0 = rowg0 & 1023;
        ushort4 pk;
        pk.x = f2b(acc[fr][fc][0]); pk.y = f2b(acc[fr][fc][1]);
        pk.z = f2b(acc[fr][fc][2]); pk.w = f2b(acc[fr][fc][3]);
        *(ushort4*)&Ch[(((size_t)(b * 16 + h) * 64) + e) * 1024 + t0] = pk;
      }
    }
  }
}

// ---------------- MFMA flash attention ------------------------------------
// q,k: [B][H][T][64] bf16; vt: [B][H][64][T] bf16; out ob: [NT][D] bf16
// block = 4 waves; wave owns 16 q rows; q-tile = 64; KV step = 64; causal.
__global__ __launch_bounds__(256) void fattn_kernel(
    const unsigned short* __restrict__ qg, const unsigned short* __restrict__ kg,
    const unsigned short* __restrict__ vtg, unsigned short* __restrict__ ob) {
  const int bid = blockIdx.x;
  const int qt = bid & 15, bh = bid >> 4;
  const int b = bh >> 4, h = bh & 15;
  const int tid = threadIdx.x, lane = tid & 63, w = tid >> 6, g = lane >> 4;

  __shared__ __align__(16) unsigned short Ks[64 * 64];   // K[s][d] swizzled 16B slots
  __shared__ __align__(16) unsigned short Vs[64 * 64];   // Vt[d][s] swizzled
  __shared__ __align__(16) unsigned short Pb[4][16 * 64]; // per-wave P[q][s] swizzled

  const unsigned short* kbase = kg + (size_t)bh * Tn * HDn;
  const unsigned short* vbase = vtg + (size_t)bh * HDn * Tn;

  // Q fragments: lane holds Q[q=lane&15][d = g*8..+7 (+32)]
  const int qrow = qt * 64 + w * 16 + (lane & 15);
  const unsigned short* qptr = qg + ((size_t)bh * Tn + qrow) * HDn;
  bf16x8 qf0 = *(const bf16x8*)(qptr + g * 8);
  bf16x8 qf1 = *(const bf16x8*)(qptr + 32 + g * 8);

  f32x4 accO[4];
  #pragma unroll
  for (int dt = 0; dt < 4; ++dt) accO[dt] = (f32x4){0.f, 0.f, 0.f, 0.f};
  float mrun[4] = {-1e30f, -1e30f, -1e30f, -1e30f};
  float lrun[4] = {0.f, 0.f, 0.f, 0.f};

  const float scale = 0.03125f;                 // D^-0.5 (reference uses n_embd)
  const int qout0 = qt * 64 + w * 16 + 4 * g;   // output rows qout0 + i

  unsigned short* pb = &Pb[w][0];
  const int nsteps = qt + 1;

  for (int st = 0; st < nsteps; ++st) {
    const int s0 = st * 64;
    __syncthreads();
    #pragma unroll
    for (int r = 0; r < 2; ++r) {
      int c = tid + 256 * r;
      int srow = c >> 3, u = c & 7;
      GLOAD_LDS16(kbase + (size_t)(s0 + srow) * HDn + ((u ^ (srow & 7)) * 8), &Ks[c * 8]);
    }
    #pragma unroll
    for (int r = 0; r < 2; ++r) {
      int c = tid + 256 * r;
      int d = c >> 3, u = c & 7;
      GLOAD_LDS16(vbase + (size_t)d * Tn + s0 + ((u ^ (d & 7)) * 8), &Vs[c * 8]);
    }
    __syncthreads();

    // S = Q K^T  (4 k-subtiles of 16)
    float p[4][4];                       // [sub][i]
    #pragma unroll
    for (int sub = 0; sub < 4; ++sub) {
      int srow = sub * 16 + (lane & 15);
      const char* kr = (const char*)Ks + srow * 128;
      bf16x8 kf0 = *(const bf16x8*)(kr + ((g ^ (srow & 7)) * 16));
      bf16x8 kf1 = *(const bf16x8*)(kr + (((4 + g) ^ (srow & 7)) * 16));
      f32x4 s4 = (f32x4){0.f, 0.f, 0.f, 0.f};
      s4 = __builtin_amdgcn_mfma_f32_16x16x32_bf16(qf0, kf0, s4, 0, 0, 0);
      s4 = __builtin_amdgcn_mfma_f32_16x16x32_bf16(qf1, kf1, s4, 0, 0, 0);
      int sg = s0 + srow;                // this lane's S column (key index)
      #pragma unroll
      for (int i = 0; i < 4; ++i)
        p[sub][i] = (sg > qout0 + i) ? -1e30f : s4[i] * scale;
    }

    // online softmax (rows spread over 16 lanes)
    #pragma unroll
    for (int i = 0; i < 4; ++i) {
      float v = fmaxf(fmaxf(p[0][i], p[1][i]), fmaxf(p[2][i], p[3][i]));
      v = fmaxf(v, __shfl_xor(v, 1)); v = fmaxf(v, __shfl_xor(v, 2));
      v = fmaxf(v, __shfl_xor(v, 4)); v = fmaxf(v, __shfl_xor(v, 8));
      float nm = fmaxf(mrun[i], v);
      float fac = __expf(mrun[i] - nm);
      mrun[i] = nm;
      #pragma unroll
      for (int dt = 0; dt < 4; ++dt) accO[dt][i] *= fac;
      float sum = 0.f;
      #pragma unroll
      for (int sub = 0; sub < 4; ++sub) {
        float e = __expf(p[sub][i] - nm);
        p[sub][i] = e;
        sum += e;
      }
      sum += __shfl_xor(sum, 1); sum += __shfl_xor(sum, 2);
      sum += __shfl_xor(sum, 4); sum += __shfl_xor(sum, 8);
      lrun[i] = lrun[i] * fac + sum;
    }

    // P -> per-wave LDS (swizzled rows of 128B)
    #pragma unroll
    for (int sub = 0; sub < 4; ++sub) {
      int s = sub * 16 + (lane & 15);
      #pragma unroll
      for (int i = 0; i < 4; ++i) {
        int q = 4 * g + i;
        pb[q * 64 + (((s >> 3) ^ (q & 7)) * 8) + (s & 7)] = f2b(p[sub][i]);
      }
    }

    // PV: O[q][d] += P[q][s] * Vt[d][s]
    #pragma unroll
    for (int sc = 0; sc < 2; ++sc) {
      int qq = lane & 15;
      bf16x8 pa = *(const bf16x8*)((const char*)pb + qq * 128 + (((sc * 4 + g) ^ (qq & 7)) * 16));
      #pragma unroll
      for (int dt = 0; dt < 4; ++dt) {
        int d = dt * 16 + (lane & 15);
        bf16x8 vf = *(const bf16x8*)((const char*)Vs + d * 128 + (((sc * 4 + g) ^ (d & 7)) * 16));
        accO[dt] = __builtin_amdgcn_mfma_f32_16x16x32_bf16(pa, vf, accO[dt], 0, 0, 0);
      }
    }
  }

  float rinv[4];
  #pragma unroll
  for (int i = 0; i < 4; ++i) rinv[i] = 1.0f / lrun[i];
  #pragma unroll
  for (int dt = 0; dt < 4; ++dt) {
    int dcol = h * 64 + dt * 16 + (lane & 15);
    #pragma unroll
    for (int i = 0; i < 4; ++i) {
      int t = qout0 + i;
      ob[((size_t)(b * Tn + t)) * Dn + dcol] = f2b(accO[dt][i] * rinv[i]);
    }
  }
}

// ---------------- per-row NLL over V=32000 (fp32 logits) -------------------
__global__ __launch_bounds__(256) void nll_kernel(
    const float* __restrict__ logits, const int* __restrict__ target,
    float* __restrict__ nll) {
  int row = blockIdx.x;
  const float* lr = logits + (size_t)row * Vn;
  const float4* l4 = (const float4*)lr;
  __shared__ float red[4];
  int lane = threadIdx.x & 63, w = threadIdx.x >> 6;

  float lmax = -1e30f;
  for (int i = threadIdx.x; i < Vn / 4; i += 256) {
    float4 v = l4[i];
    lmax = fmaxf(lmax, fmaxf(fmaxf(v.x, v.y), fmaxf(v.z, v.w)));
  }
  #pragma unroll
  for (int off = 32; off > 0; off >>= 1) lmax = fmaxf(lmax, __shfl_down(lmax, off, 64));
  if (lane == 0) red[w] = lmax;
  __syncthreads();
  float mx = fmaxf(fmaxf(red[0], red[1]), fmaxf(red[2], red[3]));
  __syncthreads();

  float lsum = 0.f;
  for (int i = threadIdx.x; i < Vn / 4; i += 256) {
    float4 v = l4[i];
    lsum += __expf(v.x - mx) + __expf(v.y - mx) + __expf(v.z - mx) + __expf(v.w - mx);
  }
  #pragma unroll
  for (int off = 32; off > 0; off >>= 1) lsum += __shfl_down(lsum, off, 64);
  if (lane == 0) red[w] = lsum;
  __syncthreads();
  if (threadIdx.x == 0) {
    float sum = red[0] + red[1] + red[2] + red[3];
    nll[row] = -(lr[target[row]] - mx - logf(sum));
  }
}

__global__ __launch_bounds__(256) void loss_kernel(
    const float* __restrict__ nll, float* __restrict__ out_loss) {
  __shared__ float red[4];
  int lane = threadIdx.x & 63, w = threadIdx.x >> 6;
  float s = 0.f;
  for (int i = threadIdx.x; i < NT; i += 256) s += nll[i];
  #pragma unroll
  for (int off = 32; off > 0; off >>= 1) s += __shfl_down(s, off, 64);
  if (lane == 0) red[w] = s;
  __syncthreads();
  if (threadIdx.x == 0)
    *out_loss = (red[0] + red[1] + red[2] + red[3]) * (1.0f / NT);
}

// ---------------------------------------------------------------------------
static inline void launch_wcast(const float* src, unsigned short* dst, int K, int M,
                                long long bsk, long long bsh, hipStream_t s) {
  dim3 g(M >> 5, K >> 5);
  wcast_kernel<<<g, 256, 0, s>>>(src, dst, K, M, bsk, bsh);
}

static inline void launch_mm(const unsigned short* A, const unsigned short* BT,
                             const float* bias, const float* res,
                             float* Cf, unsigned short* Ch,
                             int N, int K, int M, int relu, int omode, hipStream_t s) {
  dim3 g(M >> 7, N >> 7);
  mm_bf16<<<g, 256, 0, s>>>(A, BT, bias, res, Cf, Ch, N, K, M, relu, omode);
}

extern "C" void kernel_launch(void* const* d_in, const int* in_sizes, int n_in,
                              void* d_out, int out_size, void* d_ws, size_t ws_size,
                              hipStream_t stream) {
  const int*   idx    = (const int*)d_in[0];
  const int*   target = (const int*)d_in[1];
  const float* tok    = (const float*)d_in[2];
  const float* pos    = (const float*)d_in[3];
  const float* wq     = (const float*)d_in[4];
  const float* wk     = (const float*)d_in[5];
  const float* wv     = (const float*)d_in[6];
  const float* wproj  = (const float*)d_in[7];
  const float* bproj  = (const float*)d_in[8];
  const float* ln1g   = (const float*)d_in[9];
  const float* ln1b   = (const float*)d_in[10];
  const float* ln2g   = (const float*)d_in[11];
  const float* ln2b   = (const float*)d_in[12];
  const float* w1     = (const float*)d_in[13];
  const float* b1     = (const float*)d_in[14];
  const float* w2     = (const float*)d_in[15];
  const float* b2     = (const float*)d_in[16];
  const float* lnfg   = (const float*)d_in[17];
  const float* lnfb   = (const float*)d_in[18];
  const float* wlm    = (const float*)d_in[19];
  const float* blm    = (const float*)d_in[20];

  float* out = (float*)d_out;          // logits [4096,32000] + loss scalar

  char* p = (char*)d_ws;
  float* x  = (float*)p;                 p += (size_t)NT * Dn * 4;
  unsigned short* xn = (unsigned short*)p; p += (size_t)NT * Dn * 2;
  unsigned short* reg = (unsigned short*)p; p += (size_t)NT * 4 * Dn * 2;
  unsigned short* wT = (unsigned short*)p; p += (size_t)Vn * Dn * 2;
  float* nll = (float*)p;

  unsigned short* qb  = reg;                         // [B][H][T][64]
  unsigned short* kb  = reg + (size_t)NT * Dn;       // [B][H][T][64]
  unsigned short* vtb = reg + 2 * (size_t)NT * Dn;   // [B][H][64][T]
  unsigned short* ob  = reg + 3 * (size_t)NT * Dn;   // [NT][D]
  unsigned short* hb  = reg;                         // MLP hidden, disjoint in time

  embed_kernel<<<NT, 256, 0, stream>>>(idx, tok, pos, x);

  for (int l = 0; l < Ln; ++l) {
    const float* wq_l = wq + (size_t)l * Hn * Dn * HDn;
    const float* wk_l = wk + (size_t)l * Hn * Dn * HDn;
    const float* wv_l = wv + (size_t)l * Hn * Dn * HDn;

    ln_kernel<<<NT, 256, 0, stream>>>(x, ln1g + l * Dn, ln1b + l * Dn, xn);

    launch_wcast(wq_l, wT, Dn, Dn, HDn, (long long)Dn * HDn, stream);
    launch_mm(xn, wT, nullptr, nullptr, nullptr, qb, NT, Dn, Dn, 0, 1, stream);
    launch_wcast(wk_l, wT, Dn, Dn, HDn, (long long)Dn * HDn, stream);
    launch_mm(xn, wT, nullptr, nullptr, nullptr, kb, NT, Dn, Dn, 0, 1, stream);
    launch_wcast(wv_l, wT, Dn, Dn, HDn, (long long)Dn * HDn, stream);
    launch_mm(xn, wT, nullptr, nullptr, nullptr, vtb, NT, Dn, Dn, 0, 2, stream);

    fattn_kernel<<<Bn * Hn * (Tn / 64), 256, 0, stream>>>(qb, kb, vtb, ob);

    launch_wcast(wproj + (size_t)l * Dn * Dn, wT, Dn, Dn, Dn, 64, stream);
    launch_mm(ob, wT, bproj + l * Dn, x, x, nullptr, NT, Dn, Dn, 0, 0, stream);

    ln_kernel<<<NT, 256, 0, stream>>>(x, ln2g + l * Dn, ln2b + l * Dn, xn);

    launch_wcast(w1 + (size_t)l * Dn * 4 * Dn, wT, Dn, 4 * Dn, 4 * Dn, 64, stream);
    launch_mm(xn, wT, b1 + l * 4 * Dn, nullptr, nullptr, hb, NT, Dn, 4 * Dn, 1, 0, stream);
    launch_wcast(w2 + (size_t)l * 4 * Dn * Dn, wT, 4 * Dn, Dn, Dn, 64, stream);
    launch_mm(hb, wT, b2 + l * Dn, x, x, nullptr, NT, 4 * Dn, Dn, 0, 0, stream);
  }

  ln_kernel<<<NT, 256, 0, stream>>>(x, lnfg, lnfb, xn);

  launch_wcast(wlm, wT, Dn, Vn, Vn, 64, stream);
  launch_mm(xn, wT, blm, nullptr, out, nullptr, NT, Dn, Vn, 0, 0, stream);

  nll_kernel<<<NT, 256, 0, stream>>>(out, target, nll);
  loss_kernel<<<1, 256, 0, stream>>>(nll, out + (size_t)NT * Vn);
}

// Round 4
// 1641.791 us; speedup vs baseline: 8.2206x; 1.1213x over previous
//
#include <hip/hip_runtime.h>
#include <math.h>

// Problem constants
#define Dn   1024
#define Hn   16
#define HDn  64
#define Tn   1024
#define Bn   4
#define Vn   32000
#define Ln   3
#define NT   (Bn*Tn)        // 4096 token rows

typedef __attribute__((ext_vector_type(8))) short bf16x8;
typedef __attribute__((ext_vector_type(4))) float f32x4;
typedef __attribute__((ext_vector_type(8))) unsigned short u16x8;

__device__ __forceinline__ float b2f(unsigned short u) {
  union { float f; unsigned int i; } c; c.i = ((unsigned int)u) << 16; return c.f;
}
__device__ __forceinline__ unsigned short f2b(float f) {
  union { float f; unsigned int i; } c; c.f = f;
  unsigned int r = (c.i + 0x7FFFu + ((c.i >> 16) & 1u)) >> 16;
  return (unsigned short)r;
}

#define GLOAD_LDS16(g, l) __builtin_amdgcn_global_load_lds( \
    (const __attribute__((address_space(1))) void*)(g),     \
    (__attribute__((address_space(3))) void*)(l), 16, 0, 0)

// ---------------- embedding: x = tok_emb[idx] + pos_emb[t] (fp32) ----------
__global__ __launch_bounds__(256) void embed_kernel(
    const int* __restrict__ idx, const float* __restrict__ tok,
    const float* __restrict__ pos, float* __restrict__ x) {
  int row = blockIdx.x;
  int t = row & (Tn - 1);
  int token = idx[row];
  const float4* tp = (const float4*)(tok + (size_t)token * Dn);
  const float4* pp = (const float4*)(pos + (size_t)t * Dn);
  float4* xp = (float4*)(x + (size_t)row * Dn);
  int i = threadIdx.x;
  float4 a = tp[i], b = pp[i];
  xp[i] = make_float4(a.x + b.x, a.y + b.y, a.z + b.z, a.w + b.w);
}

// ---------------- LayerNorm: fp32 in, bf16 out -----------------------------
__global__ __launch_bounds__(256) void ln_kernel(
    const float* __restrict__ x, const float* __restrict__ g,
    const float* __restrict__ b, unsigned short* __restrict__ y) {
  int row = blockIdx.x;
  const float4* xr = (const float4*)(x + (size_t)row * Dn);
  __shared__ float red[4];
  int lane = threadIdx.x & 63, w = threadIdx.x >> 6;

  float4 v = xr[threadIdx.x];
  float s = v.x + v.y + v.z + v.w;
  #pragma unroll
  for (int o = 32; o > 0; o >>= 1) s += __shfl_down(s, o, 64);
  if (lane == 0) red[w] = s;
  __syncthreads();
  float mu = (red[0] + red[1] + red[2] + red[3]) * (1.0f / Dn);
  __syncthreads();

  float dx = v.x - mu, dy = v.y - mu, dz = v.z - mu, dw = v.w - mu;
  float ss = dx*dx + dy*dy + dz*dz + dw*dw;
  #pragma unroll
  for (int o = 32; o > 0; o >>= 1) ss += __shfl_down(ss, o, 64);
  if (lane == 0) red[w] = ss;
  __syncthreads();
  float var = (red[0] + red[1] + red[2] + red[3]) * (1.0f / Dn);
  float inv = rsqrtf(var + 1e-5f);

  float4 gv = ((const float4*)g)[threadIdx.x];
  float4 bv = ((const float4*)b)[threadIdx.x];
  ushort4 o4;
  o4.x = f2b(dx*inv*gv.x + bv.x);
  o4.y = f2b(dy*inv*gv.y + bv.y);
  o4.z = f2b(dz*inv*gv.z + bv.z);
  o4.w = f2b(dw*inv*gv.w + bv.w);
  ((ushort4*)(y + (size_t)row * Dn))[threadIdx.x] = o4;
}

// ---------------- weight transpose-cast: fp32 B(k,m) -> bf16 BT[m][k] ------
__global__ __launch_bounds__(256) void wcast_kernel(
    const float* __restrict__ src, unsigned short* __restrict__ dst,
    int K, int M, long long bsk, long long bsh) {
  __shared__ float t[32][33];
  int m0 = blockIdx.x << 5, k0 = blockIdx.y << 5;
  int tid = threadIdx.x;
  int ml = tid & 31, kl = tid >> 5;
  #pragma unroll
  for (int p = 0; p < 4; ++p) {
    int k = k0 + kl + p * 8;
    int m = m0 + ml;
    t[ml][kl + p * 8] = src[(size_t)k * bsk + (size_t)(m >> 6) * bsh + (m & 63)];
  }
  __syncthreads();
  int kl2 = tid & 31, ml2 = tid >> 5;
  #pragma unroll
  for (int p = 0; p < 4; ++p) {
    int m = m0 + ml2 + p * 8;
    int k = k0 + kl2;
    dst[(size_t)m * K + k] = f2b(t[ml2 + p * 8][kl2]);
  }
}

// ---------------- bf16 MFMA GEMM (128x128 tile, BK=64) ---------------------
// grid = (N/128, M/128): n-block is the FAST axis so consecutive blocks share
// the same B-panel (B stays L3/L2-resident; A is small and L3-resident).
// omode 0: row-major out (Cf fp32 or Ch bf16), bias/res/relu supported
// omode 3: fused QKV (M=3072): cols [0,1024)->Q [B][H][T][64],
//          [1024,2048)->K same layout, [2048,3072)->V transposed [B][H][64][T]
__global__ __launch_bounds__(256) void mm_bf16(
    const unsigned short* __restrict__ A, const unsigned short* __restrict__ BT,
    const float* __restrict__ bias, const float* __restrict__ res,
    float* __restrict__ Cf, unsigned short* __restrict__ Ch,
    int N, int K, int M, int relu, int omode) {
  __shared__ __align__(16) unsigned short As[128 * 64];
  __shared__ __align__(16) unsigned short Bs[128 * 64];
  const int tid = threadIdx.x;
  const int lane = tid & 63, w = tid >> 6, g = lane >> 4;
  const int wr = w >> 1, wc = w & 1;
  const int n0 = blockIdx.x << 7, m0 = blockIdx.y << 7;

  f32x4 acc[4][4];
  #pragma unroll
  for (int i = 0; i < 4; ++i)
    #pragma unroll
    for (int j = 0; j < 4; ++j)
      acc[i][j] = (f32x4){0.f, 0.f, 0.f, 0.f};

  // staging: LDS rows of 64 bf16 (128B = 8 x 16B slots); physical slot u at
  // row r holds logical k-slot (u ^ (r&7)). Linear LDS dest (rule #21),
  // inverse-swizzled global source. 4 chunks per thread per matrix.
  int soff[4];
  #pragma unroll
  for (int r2 = 0; r2 < 4; ++r2) {
    int c = tid + 256 * r2;          // 16B chunk index, 1024 per matrix
    int row = c >> 3, u = c & 7;
    soff[r2] = row * K + ((u ^ (row & 7)) << 3);
  }
  const unsigned short* Abase = A + (size_t)n0 * K;
  const unsigned short* Bbase = BT + (size_t)m0 * K;

  // fragment read byte offsets (swizzled): logical slot = g + kk_idx*4
  int a_off[2][4], b_off[2][4];
  #pragma unroll
  for (int f = 0; f < 4; ++f) {
    int ra = wr * 64 + f * 16 + (lane & 15);
    int rb = wc * 64 + f * 16 + (lane & 15);
    #pragma unroll
    for (int kkid = 0; kkid < 2; ++kkid) {
      int slog = g + kkid * 4;
      a_off[kkid][f] = ra * 128 + ((slog ^ (ra & 7)) << 4);
      b_off[kkid][f] = rb * 128 + ((slog ^ (rb & 7)) << 4);
    }
  }

  for (int k0 = 0; k0 < K; k0 += 64) {
    __syncthreads();
    #pragma unroll
    for (int r2 = 0; r2 < 4; ++r2)
      GLOAD_LDS16(Abase + soff[r2] + k0, As + (tid + 256 * r2) * 8);
    #pragma unroll
    for (int r2 = 0; r2 < 4; ++r2)
      GLOAD_LDS16(Bbase + soff[r2] + k0, Bs + (tid + 256 * r2) * 8);
    __syncthreads();

    #pragma unroll
    for (int kkid = 0; kkid < 2; ++kkid) {
      bf16x8 af[4], bfr[4];
      #pragma unroll
      for (int f = 0; f < 4; ++f) {
        af[f]  = *(const bf16x8*)((const char*)As + a_off[kkid][f]);
        bfr[f] = *(const bf16x8*)((const char*)Bs + b_off[kkid][f]);
      }
      #pragma unroll
      for (int i = 0; i < 4; ++i)
        #pragma unroll
        for (int j = 0; j < 4; ++j)
          acc[i][j] = __builtin_amdgcn_mfma_f32_16x16x32_bf16(af[i], bfr[j], acc[i][j], 0, 0, 0);
    }
  }

  if (omode == 0) {
    #pragma unroll
    for (int fc = 0; fc < 4; ++fc) {
      int colg = m0 + wc * 64 + fc * 16 + (lane & 15);
      float bz = bias ? bias[colg] : 0.f;
      #pragma unroll
      for (int fr = 0; fr < 4; ++fr) {
        #pragma unroll
        for (int i = 0; i < 4; ++i) {
          int rowg = n0 + wr * 64 + fr * 16 + (g << 2) + i;
          float v = acc[fr][fc][i] + bz;
          if (res) v += res[(size_t)rowg * M + colg];
          if (relu) v = fmaxf(v, 0.f);
          if (Cf) Cf[(size_t)rowg * M + colg] = v;
          else    Ch[(size_t)rowg * M + colg] = f2b(v);
        }
      }
    }
  } else {
    // fused QKV epilogue. Ch = base of {q | k | vt} region.
    unsigned short* kb  = Ch + (size_t)NT * Dn;
    unsigned short* vtb = Ch + 2 * (size_t)NT * Dn;
    #pragma unroll
    for (int fc = 0; fc < 4; ++fc) {
      int colg = m0 + wc * 64 + fc * 16 + (lane & 15);
      int sel = colg >> 10, hh = (colg >> 6) & 15, e = colg & 63;
      #pragma unroll
      for (int fr = 0; fr < 4; ++fr) {
        int rowg0 = n0 + wr * 64 + fr * 16 + (g << 2);
        int b = rowg0 >> 10, t0 = rowg0 & 1023;
        if (sel == 2) {
          ushort4 pk;
          pk.x = f2b(acc[fr][fc][0]); pk.y = f2b(acc[fr][fc][1]);
          pk.z = f2b(acc[fr][fc][2]); pk.w = f2b(acc[fr][fc][3]);
          *(ushort4*)&vtb[(((size_t)(b * 16 + hh) * 64) + e) * 1024 + t0] = pk;
        } else {
          unsigned short* dst = (sel == 0) ? Ch : kb;
          #pragma unroll
          for (int i = 0; i < 4; ++i)
            dst[(((size_t)(b * 16 + hh) * 1024) + t0 + i) * 64 + e] = f2b(acc[fr][fc][i]);
        }
      }
    }
  }
}

// ---------------- MFMA flash attention ------------------------------------
// q,k: [B][H][T][64] bf16; vt: [B][H][64][T] bf16; out ob: [NT][D] bf16
__global__ __launch_bounds__(256) void fattn_kernel(
    const unsigned short* __restrict__ qg, const unsigned short* __restrict__ kg,
    const unsigned short* __restrict__ vtg, unsigned short* __restrict__ ob) {
  const int bid = blockIdx.x;
  const int qt = bid & 15, bh = bid >> 4;
  const int b = bh >> 4, h = bh & 15;
  const int tid = threadIdx.x, lane = tid & 63, w = tid >> 6, g = lane >> 4;

  __shared__ __align__(16) unsigned short Ks[64 * 64];
  __shared__ __align__(16) unsigned short Vs[64 * 64];
  __shared__ __align__(16) unsigned short Pb[4][16 * 64];

  const unsigned short* kbase = kg + (size_t)bh * Tn * HDn;
  const unsigned short* vbase = vtg + (size_t)bh * HDn * Tn;

  const int qrow = qt * 64 + w * 16 + (lane & 15);
  const unsigned short* qptr = qg + ((size_t)bh * Tn + qrow) * HDn;
  bf16x8 qf0 = *(const bf16x8*)(qptr + g * 8);
  bf16x8 qf1 = *(const bf16x8*)(qptr + 32 + g * 8);

  f32x4 accO[4];
  #pragma unroll
  for (int dt = 0; dt < 4; ++dt) accO[dt] = (f32x4){0.f, 0.f, 0.f, 0.f};
  float mrun[4] = {-1e30f, -1e30f, -1e30f, -1e30f};
  float lrun[4] = {0.f, 0.f, 0.f, 0.f};

  const float scale = 0.03125f;                 // D^-0.5 (reference scales by n_embd)
  const int qout0 = qt * 64 + w * 16 + 4 * g;

  unsigned short* pb = &Pb[w][0];
  const int nsteps = qt + 1;

  for (int st = 0; st < nsteps; ++st) {
    const int s0 = st * 64;
    __syncthreads();
    #pragma unroll
    for (int r = 0; r < 2; ++r) {
      int c = tid + 256 * r;
      int srow = c >> 3, u = c & 7;
      GLOAD_LDS16(kbase + (size_t)(s0 + srow) * HDn + ((u ^ (srow & 7)) * 8), &Ks[c * 8]);
    }
    #pragma unroll
    for (int r = 0; r < 2; ++r) {
      int c = tid + 256 * r;
      int d = c >> 3, u = c & 7;
      GLOAD_LDS16(vbase + (size_t)d * Tn + s0 + ((u ^ (d & 7)) * 8), &Vs[c * 8]);
    }
    __syncthreads();

    float p[4][4];
    #pragma unroll
    for (int sub = 0; sub < 4; ++sub) {
      int srow = sub * 16 + (lane & 15);
      const char* kr = (const char*)Ks + srow * 128;
      bf16x8 kf0 = *(const bf16x8*)(kr + ((g ^ (srow & 7)) * 16));
      bf16x8 kf1 = *(const bf16x8*)(kr + (((4 + g) ^ (srow & 7)) * 16));
      f32x4 s4 = (f32x4){0.f, 0.f, 0.f, 0.f};
      s4 = __builtin_amdgcn_mfma_f32_16x16x32_bf16(qf0, kf0, s4, 0, 0, 0);
      s4 = __builtin_amdgcn_mfma_f32_16x16x32_bf16(qf1, kf1, s4, 0, 0, 0);
      int sg = s0 + srow;
      #pragma unroll
      for (int i = 0; i < 4; ++i)
        p[sub][i] = (sg > qout0 + i) ? -1e30f : s4[i] * scale;
    }

    #pragma unroll
    for (int i = 0; i < 4; ++i) {
      float v = fmaxf(fmaxf(p[0][i], p[1][i]), fmaxf(p[2][i], p[3][i]));
      v = fmaxf(v, __shfl_xor(v, 1)); v = fmaxf(v, __shfl_xor(v, 2));
      v = fmaxf(v, __shfl_xor(v, 4)); v = fmaxf(v, __shfl_xor(v, 8));
      float nm = fmaxf(mrun[i], v);
      float fac = __expf(mrun[i] - nm);
      mrun[i] = nm;
      #pragma unroll
      for (int dt = 0; dt < 4; ++dt) accO[dt][i] *= fac;
      float sum = 0.f;
      #pragma unroll
      for (int sub = 0; sub < 4; ++sub) {
        float e = __expf(p[sub][i] - nm);
        p[sub][i] = e;
        sum += e;
      }
      sum += __shfl_xor(sum, 1); sum += __shfl_xor(sum, 2);
      sum += __shfl_xor(sum, 4); sum += __shfl_xor(sum, 8);
      lrun[i] = lrun[i] * fac + sum;
    }

    #pragma unroll
    for (int sub = 0; sub < 4; ++sub) {
      int s = sub * 16 + (lane & 15);
      #pragma unroll
      for (int i = 0; i < 4; ++i) {
        int q = 4 * g + i;
        pb[q * 64 + (((s >> 3) ^ (q & 7)) * 8) + (s & 7)] = f2b(p[sub][i]);
      }
    }

    #pragma unroll
    for (int sc = 0; sc < 2; ++sc) {
      int qq = lane & 15;
      bf16x8 pa = *(const bf16x8*)((const char*)pb + qq * 128 + (((sc * 4 + g) ^ (qq & 7)) * 16));
      #pragma unroll
      for (int dt = 0; dt < 4; ++dt) {
        int d = dt * 16 + (lane & 15);
        bf16x8 vf = *(const bf16x8*)((const char*)Vs + d * 128 + (((sc * 4 + g) ^ (d & 7)) * 16));
        accO[dt] = __builtin_amdgcn_mfma_f32_16x16x32_bf16(pa, vf, accO[dt], 0, 0, 0);
      }
    }
  }

  float rinv[4];
  #pragma unroll
  for (int i = 0; i < 4; ++i) rinv[i] = 1.0f / lrun[i];
  #pragma unroll
  for (int dt = 0; dt < 4; ++dt) {
    int dcol = h * 64 + dt * 16 + (lane & 15);
    #pragma unroll
    for (int i = 0; i < 4; ++i) {
      int t = qout0 + i;
      ob[((size_t)(b * Tn + t)) * Dn + dcol] = f2b(accO[dt][i] * rinv[i]);
    }
  }
}

// ---------------- single-pass online NLL over V=32000 ----------------------
__global__ __launch_bounds__(256) void nll_kernel(
    const float* __restrict__ logits, const int* __restrict__ target,
    float* __restrict__ nll) {
  int row = blockIdx.x;
  const float* lr = logits + (size_t)row * Vn;
  const float4* l4 = (const float4*)lr;
  __shared__ float rm[4], rs[4];
  int lane = threadIdx.x & 63, w = threadIdx.x >> 6;

  float m = -1e30f, s = 0.f;
  for (int i = threadIdx.x; i < Vn / 4; i += 256) {
    float4 v = l4[i];
    float m4 = fmaxf(fmaxf(v.x, v.y), fmaxf(v.z, v.w));
    if (m4 > m) { s *= __expf(m - m4); m = m4; }
    s += __expf(v.x - m) + __expf(v.y - m) + __expf(v.z - m) + __expf(v.w - m);
  }
  #pragma unroll
  for (int off = 32; off > 0; off >>= 1) {
    float mo = __shfl_xor(m, off), so = __shfl_xor(s, off);
    float M = fmaxf(m, mo);
    s = s * __expf(m - M) + so * __expf(mo - M);
    m = M;
  }
  if (lane == 0) { rm[w] = m; rs[w] = s; }
  __syncthreads();
  if (threadIdx.x == 0) {
    float M = fmaxf(fmaxf(rm[0], rm[1]), fmaxf(rm[2], rm[3]));
    float S = rs[0] * __expf(rm[0] - M) + rs[1] * __expf(rm[1] - M) +
              rs[2] * __expf(rm[2] - M) + rs[3] * __expf(rm[3] - M);
    nll[row] = -(lr[target[row]] - M - logf(S));
  }
}

__global__ __launch_bounds__(256) void loss_kernel(
    const float* __restrict__ nll, float* __restrict__ out_loss) {
  __shared__ float red[4];
  int lane = threadIdx.x & 63, w = threadIdx.x >> 6;
  float s = 0.f;
  for (int i = threadIdx.x; i < NT; i += 256) s += nll[i];
  #pragma unroll
  for (int off = 32; off > 0; off >>= 1) s += __shfl_down(s, off, 64);
  if (lane == 0) red[w] = s;
  __syncthreads();
  if (threadIdx.x == 0)
    *out_loss = (red[0] + red[1] + red[2] + red[3]) * (1.0f / NT);
}

// ---------------------------------------------------------------------------
static inline void launch_wcast(const float* src, unsigned short* dst, int K, int M,
                                long long bsk, long long bsh, hipStream_t s) {
  dim3 g(M >> 5, K >> 5);
  wcast_kernel<<<g, 256, 0, s>>>(src, dst, K, M, bsk, bsh);
}

static inline void launch_mm(const unsigned short* A, const unsigned short* BT,
                             const float* bias, const float* res,
                             float* Cf, unsigned short* Ch,
                             int N, int K, int M, int relu, int omode, hipStream_t s) {
  dim3 g(N >> 7, M >> 7);          // n fast, m slow: B-panel temporal locality
  mm_bf16<<<g, 256, 0, s>>>(A, BT, bias, res, Cf, Ch, N, K, M, relu, omode);
}

extern "C" void kernel_launch(void* const* d_in, const int* in_sizes, int n_in,
                              void* d_out, int out_size, void* d_ws, size_t ws_size,
                              hipStream_t stream) {
  const int*   idx    = (const int*)d_in[0];
  const int*   target = (const int*)d_in[1];
  const float* tok    = (const float*)d_in[2];
  const float* pos    = (const float*)d_in[3];
  const float* wq     = (const float*)d_in[4];
  const float* wk     = (const float*)d_in[5];
  const float* wv     = (const float*)d_in[6];
  const float* wproj  = (const float*)d_in[7];
  const float* bproj  = (const float*)d_in[8];
  const float* ln1g   = (const float*)d_in[9];
  const float* ln1b   = (const float*)d_in[10];
  const float* ln2g   = (const float*)d_in[11];
  const float* ln2b   = (const float*)d_in[12];
  const float* w1     = (const float*)d_in[13];
  const float* b1     = (const float*)d_in[14];
  const float* w2     = (const float*)d_in[15];
  const float* b2     = (const float*)d_in[16];
  const float* lnfg   = (const float*)d_in[17];
  const float* lnfb   = (const float*)d_in[18];
  const float* wlm    = (const float*)d_in[19];
  const float* blm    = (const float*)d_in[20];

  float* out = (float*)d_out;          // logits [4096,32000] + loss scalar

  char* p = (char*)d_ws;
  float* x  = (float*)p;                 p += (size_t)NT * Dn * 4;
  unsigned short* xn = (unsigned short*)p; p += (size_t)NT * Dn * 2;
  unsigned short* reg = (unsigned short*)p; p += (size_t)NT * 4 * Dn * 2;
  unsigned short* wT = (unsigned short*)p; p += (size_t)Vn * Dn * 2;
  float* nll = (float*)p;

  unsigned short* qb  = reg;                         // [B][H][T][64]
  unsigned short* kb  = reg + (size_t)NT * Dn;       // [B][H][T][64]
  unsigned short* vtb = reg + 2 * (size_t)NT * Dn;   // [B][H][64][T]
  unsigned short* ob  = reg + 3 * (size_t)NT * Dn;   // [NT][D]
  unsigned short* hb  = reg;                         // MLP hidden, disjoint in time

  embed_kernel<<<NT, 256, 0, stream>>>(idx, tok, pos, x);

  for (int l = 0; l < Ln; ++l) {
    const float* wq_l = wq + (size_t)l * Hn * Dn * HDn;
    const float* wk_l = wk + (size_t)l * Hn * Dn * HDn;
    const float* wv_l = wv + (size_t)l * Hn * Dn * HDn;

    ln_kernel<<<NT, 256, 0, stream>>>(x, ln1g + l * Dn, ln1b + l * Dn, xn);

    // fused QKV: wT rows [0,1024)=q, [1024,2048)=k, [2048,3072)=v
    launch_wcast(wq_l, wT,                  Dn, Dn, HDn, (long long)Dn * HDn, stream);
    launch_wcast(wk_l, wT + 1024 * Dn,      Dn, Dn, HDn, (long long)Dn * HDn, stream);
    launch_wcast(wv_l, wT + 2048 * Dn,      Dn, Dn, HDn, (long long)Dn * HDn, stream);
    launch_mm(xn, wT, nullptr, nullptr, nullptr, qb, NT, Dn, 3072, 0, 3, stream);

    fattn_kernel<<<Bn * Hn * (Tn / 64), 256, 0, stream>>>(qb, kb, vtb, ob);

    launch_wcast(wproj + (size_t)l * Dn * Dn, wT, Dn, Dn, Dn, 64, stream);
    launch_mm(ob, wT, bproj + l * Dn, x, x, nullptr, NT, Dn, Dn, 0, 0, stream);

    ln_kernel<<<NT, 256, 0, stream>>>(x, ln2g + l * Dn, ln2b + l * Dn, xn);

    launch_wcast(w1 + (size_t)l * Dn * 4 * Dn, wT, Dn, 4 * Dn, 4 * Dn, 64, stream);
    launch_mm(xn, wT, b1 + l * 4 * Dn, nullptr, nullptr, hb, NT, Dn, 4 * Dn, 1, 0, stream);
    launch_wcast(w2 + (size_t)l * 4 * Dn * Dn, wT, 4 * Dn, Dn, Dn, 64, stream);
    launch_mm(hb, wT, b2 + l * Dn, x, x, nullptr, NT, 4 * Dn, Dn, 0, 0, stream);
  }

  ln_kernel<<<NT, 256, 0, stream>>>(x, lnfg, lnfb, xn);

  launch_wcast(wlm, wT, Dn, Vn, Vn, 64, stream);
  launch_mm(xn, wT, blm, nullptr, out, nullptr, NT, Dn, Vn, 0, 0, stream);

  nll_kernel<<<NT, 256, 0, stream>>>(out, target, nll);
  loss_kernel<<<1, 256, 0, stream>>>(nll, out + (size_t)NT * Vn);
}

// Round 5
// 1510.658 us; speedup vs baseline: 8.9342x; 1.0868x over previous
//
#include <hip/hip_runtime.h>
#include <math.h>

// Problem constants
#define Dn   1024
#define Hn   16
#define HDn  64
#define Tn   1024
#define Bn   4
#define Vn   32000
#define Ln   3
#define NT   (Bn*Tn)        // 4096 token rows

typedef __attribute__((ext_vector_type(8))) short bf16x8;
typedef __attribute__((ext_vector_type(4))) float f32x4;
typedef __attribute__((ext_vector_type(8))) unsigned short u16x8;

__device__ __forceinline__ float b2f(unsigned short u) {
  union { float f; unsigned int i; } c; c.i = ((unsigned int)u) << 16; return c.f;
}
__device__ __forceinline__ unsigned short f2b(float f) {
  union { float f; unsigned int i; } c; c.f = f;
  unsigned int r = (c.i + 0x7FFFu + ((c.i >> 16) & 1u)) >> 16;
  return (unsigned short)r;
}

#define GLOAD_LDS16(g, l) __builtin_amdgcn_global_load_lds( \
    (const __attribute__((address_space(1))) void*)(g),     \
    (__attribute__((address_space(3))) void*)(l), 16, 0, 0)

// ---------------- embedding: x = tok_emb[idx] + pos_emb[t] (fp32) ----------
__global__ __launch_bounds__(256) void embed_kernel(
    const int* __restrict__ idx, const float* __restrict__ tok,
    const float* __restrict__ pos, float* __restrict__ x) {
  int row = blockIdx.x;
  int t = row & (Tn - 1);
  int token = idx[row];
  const float4* tp = (const float4*)(tok + (size_t)token * Dn);
  const float4* pp = (const float4*)(pos + (size_t)t * Dn);
  float4* xp = (float4*)(x + (size_t)row * Dn);
  int i = threadIdx.x;
  float4 a = tp[i], b = pp[i];
  xp[i] = make_float4(a.x + b.x, a.y + b.y, a.z + b.z, a.w + b.w);
}

// ---------------- LayerNorm: fp32 in, bf16 out -----------------------------
__global__ __launch_bounds__(256) void ln_kernel(
    const float* __restrict__ x, const float* __restrict__ g,
    const float* __restrict__ b, unsigned short* __restrict__ y) {
  int row = blockIdx.x;
  const float4* xr = (const float4*)(x + (size_t)row * Dn);
  __shared__ float red[4];
  int lane = threadIdx.x & 63, w = threadIdx.x >> 6;

  float4 v = xr[threadIdx.x];
  float s = v.x + v.y + v.z + v.w;
  #pragma unroll
  for (int o = 32; o > 0; o >>= 1) s += __shfl_down(s, o, 64);
  if (lane == 0) red[w] = s;
  __syncthreads();
  float mu = (red[0] + red[1] + red[2] + red[3]) * (1.0f / Dn);
  __syncthreads();

  float dx = v.x - mu, dy = v.y - mu, dz = v.z - mu, dw = v.w - mu;
  float ss = dx*dx + dy*dy + dz*dz + dw*dw;
  #pragma unroll
  for (int o = 32; o > 0; o >>= 1) ss += __shfl_down(ss, o, 64);
  if (lane == 0) red[w] = ss;
  __syncthreads();
  float var = (red[0] + red[1] + red[2] + red[3]) * (1.0f / Dn);
  float inv = rsqrtf(var + 1e-5f);

  float4 gv = ((const float4*)g)[threadIdx.x];
  float4 bv = ((const float4*)b)[threadIdx.x];
  ushort4 o4;
  o4.x = f2b(dx*inv*gv.x + bv.x);
  o4.y = f2b(dy*inv*gv.y + bv.y);
  o4.z = f2b(dz*inv*gv.z + bv.z);
  o4.w = f2b(dw*inv*gv.w + bv.w);
  ((ushort4*)(y + (size_t)row * Dn))[threadIdx.x] = o4;
}

// ---------------- weight transpose-cast: fp32 B(k,m) -> bf16 BT[m][k] ------
__global__ __launch_bounds__(256) void wcast_kernel(
    const float* __restrict__ src, unsigned short* __restrict__ dst,
    int K, int M, long long bsk, long long bsh) {
  __shared__ float t[32][33];
  int m0 = blockIdx.x << 5, k0 = blockIdx.y << 5;
  int tid = threadIdx.x;
  int ml = tid & 31, kl = tid >> 5;
  #pragma unroll
  for (int p = 0; p < 4; ++p) {
    int k = k0 + kl + p * 8;
    int m = m0 + ml;
    t[ml][kl + p * 8] = src[(size_t)k * bsk + (size_t)(m >> 6) * bsh + (m & 63)];
  }
  __syncthreads();
  int kl2 = tid & 31, ml2 = tid >> 5;
  #pragma unroll
  for (int p = 0; p < 4; ++p) {
    int m = m0 + ml2 + p * 8;
    int k = k0 + kl2;
    dst[(size_t)m * K + k] = f2b(t[ml2 + p * 8][kl2]);
  }
}

// ---------------- bf16 MFMA GEMM (m97 structure, 128x128x32, BK=32) --------
// grid = (N/128, M/128): n-block fast => B-panel stays L2/L3-resident.
// OMODE 0: row-major out (Cf fp32 or Ch bf16) + bias/res/relu(runtime)
// OMODE 3: fused QKV (M=3072): cols [0,1k)->Q, [1k,2k)->K  [B][H][T][64];
//          [2k,3k)->V transposed [B][H][64][T]
// OMODE 4: LM head: Cf fp32 + bias + per-row sum(exp(logit)) atomicAdd.
template<int OMODE>
__global__ __launch_bounds__(256) void mm_bf16(
    const unsigned short* __restrict__ A, const unsigned short* __restrict__ BT,
    const float* __restrict__ bias, const float* __restrict__ res,
    float* __restrict__ Cf, unsigned short* __restrict__ Ch,
    float* __restrict__ rowsum, int N, int K, int M, int relu) {
  __shared__ __align__(16) unsigned short As[128 * 32];
  __shared__ __align__(16) unsigned short Bs[128 * 32];
  const int tid = threadIdx.x;
  const int lane = tid & 63, w = tid >> 6, g = lane >> 4;
  const int wr = w >> 1, wc = w & 1;
  const int n0 = blockIdx.x << 7, m0 = blockIdx.y << 7;

  f32x4 acc[4][4];
  #pragma unroll
  for (int i = 0; i < 4; ++i)
    #pragma unroll
    for (int j = 0; j < 4; ++j)
      acc[i][j] = (f32x4){0.f, 0.f, 0.f, 0.f};

  const int beta0 = w * 2048 + lane * 16;
  const int beta1 = beta0 + 1024;
  const int r0 = beta0 >> 6, u0 = (beta0 >> 4) & 3;
  const int r1 = beta1 >> 6, u1 = (beta1 >> 4) & 3;
  const int ks0 = u0 ^ ((r0 >> 1) & 3);
  const int ks1 = u1 ^ ((r1 >> 1) & 3);
  const unsigned short* a_g0 = A + (size_t)(n0 + r0) * K + ks0 * 8;
  const unsigned short* a_g1 = A + (size_t)(n0 + r1) * K + ks1 * 8;
  const unsigned short* b_g0 = BT + (size_t)(m0 + r0) * K + ks0 * 8;
  const unsigned short* b_g1 = BT + (size_t)(m0 + r1) * K + ks1 * 8;
  unsigned short* a_l0 = As + w * 1024;
  unsigned short* a_l1 = As + w * 1024 + 512;
  unsigned short* b_l0 = Bs + w * 1024;
  unsigned short* b_l1 = Bs + w * 1024 + 512;

  int a_off[4], b_off[4];
  #pragma unroll
  for (int f = 0; f < 4; ++f) {
    int row = wr * 64 + f * 16 + (lane & 15);
    a_off[f] = row * 64 + (((lane >> 4) ^ ((row >> 1) & 3)) << 4);
    int col = wc * 64 + f * 16 + (lane & 15);
    b_off[f] = col * 64 + (((lane >> 4) ^ ((col >> 1) & 3)) << 4);
  }

  for (int k0 = 0; k0 < K; k0 += 32) {
    __syncthreads();
    GLOAD_LDS16(a_g0 + k0, a_l0);
    GLOAD_LDS16(a_g1 + k0, a_l1);
    GLOAD_LDS16(b_g0 + k0, b_l0);
    GLOAD_LDS16(b_g1 + k0, b_l1);
    __syncthreads();

    bf16x8 af[4], bfr[4];
    #pragma unroll
    for (int f = 0; f < 4; ++f) {
      af[f]  = *(const bf16x8*)((const char*)As + a_off[f]);
      bfr[f] = *(const bf16x8*)((const char*)Bs + b_off[f]);
    }
    #pragma unroll
    for (int i = 0; i < 4; ++i)
      #pragma unroll
      for (int j = 0; j < 4; ++j)
        acc[i][j] = __builtin_amdgcn_mfma_f32_16x16x32_bf16(af[i], bfr[j], acc[i][j], 0, 0, 0);
  }

  if (OMODE == 0) {
    #pragma unroll
    for (int fc = 0; fc < 4; ++fc) {
      int colg = m0 + wc * 64 + fc * 16 + (lane & 15);
      float bz = bias ? bias[colg] : 0.f;
      #pragma unroll
      for (int fr = 0; fr < 4; ++fr) {
        #pragma unroll
        for (int i = 0; i < 4; ++i) {
          int rowg = n0 + wr * 64 + fr * 16 + (g << 2) + i;
          float v = acc[fr][fc][i] + bz;
          if (res) v += res[(size_t)rowg * M + colg];
          if (relu) v = fmaxf(v, 0.f);
          if (Cf) Cf[(size_t)rowg * M + colg] = v;
          else    Ch[(size_t)rowg * M + colg] = f2b(v);
        }
      }
    }
  } else if (OMODE == 3) {
    // fused QKV epilogue. Ch = base of {q | k | vt} region.
    unsigned short* kb  = Ch + (size_t)NT * Dn;
    unsigned short* vtb = Ch + 2 * (size_t)NT * Dn;
    #pragma unroll
    for (int fc = 0; fc < 4; ++fc) {
      int colg = m0 + wc * 64 + fc * 16 + (lane & 15);
      int sel = colg >> 10, hh = (colg >> 6) & 15, e = colg & 63;
      #pragma unroll
      for (int fr = 0; fr < 4; ++fr) {
        int rowg0 = n0 + wr * 64 + fr * 16 + (g << 2);
        int b = rowg0 >> 10, t0 = rowg0 & 1023;
        if (sel == 2) {
          ushort4 pk;
          pk.x = f2b(acc[fr][fc][0]); pk.y = f2b(acc[fr][fc][1]);
          pk.z = f2b(acc[fr][fc][2]); pk.w = f2b(acc[fr][fc][3]);
          *(ushort4*)&vtb[(((size_t)(b * 16 + hh) * 64) + e) * 1024 + t0] = pk;
        } else {
          unsigned short* dst = (sel == 0) ? Ch : kb;
          #pragma unroll
          for (int i = 0; i < 4; ++i)
            dst[(((size_t)(b * 16 + hh) * 1024) + t0 + i) * 64 + e] = f2b(acc[fr][fc][i]);
        }
      }
    }
  } else {
    // OMODE 4: LM head. Write fp32 logits + per-row partial exp-sums.
    // rsum2[row][wc]: each (wr,fr,g,i) gives a unique row in [0,128); two
    // wc-halves contribute independently -> no atomics needed in LDS.
    __shared__ float rsum2[128][2];
    #pragma unroll
    for (int fr = 0; fr < 4; ++fr) {
      #pragma unroll
      for (int i = 0; i < 4; ++i) {
        int rloc = wr * 64 + fr * 16 + (g << 2) + i;
        int rowg = n0 + rloc;
        float es = 0.f;
        #pragma unroll
        for (int fc = 0; fc < 4; ++fc) {
          int colg = m0 + wc * 64 + fc * 16 + (lane & 15);
          float v = acc[fr][fc][i] + bias[colg];
          Cf[(size_t)rowg * M + colg] = v;
          es += __expf(v);
        }
        es += __shfl_xor(es, 1); es += __shfl_xor(es, 2);
        es += __shfl_xor(es, 4); es += __shfl_xor(es, 8);
        if ((lane & 15) == 0) rsum2[rloc][wc] = es;
      }
    }
    __syncthreads();
    if (tid < 128) atomicAdd(&rowsum[n0 + tid], rsum2[tid][0] + rsum2[tid][1]);
  }
}

// ---------------- MFMA flash attention ------------------------------------
// q,k: [B][H][T][64] bf16; vt: [B][H][64][T] bf16; out ob: [NT][D] bf16
__global__ __launch_bounds__(256) void fattn_kernel(
    const unsigned short* __restrict__ qg, const unsigned short* __restrict__ kg,
    const unsigned short* __restrict__ vtg, unsigned short* __restrict__ ob) {
  const int bid = blockIdx.x;
  const int qt = bid & 15, bh = bid >> 4;
  const int b = bh >> 4, h = bh & 15;
  const int tid = threadIdx.x, lane = tid & 63, w = tid >> 6, g = lane >> 4;

  __shared__ __align__(16) unsigned short Ks[64 * 64];
  __shared__ __align__(16) unsigned short Vs[64 * 64];
  __shared__ __align__(16) unsigned short Pb[4][16 * 64];

  const unsigned short* kbase = kg + (size_t)bh * Tn * HDn;
  const unsigned short* vbase = vtg + (size_t)bh * HDn * Tn;

  const int qrow = qt * 64 + w * 16 + (lane & 15);
  const unsigned short* qptr = qg + ((size_t)bh * Tn + qrow) * HDn;
  bf16x8 qf0 = *(const bf16x8*)(qptr + g * 8);
  bf16x8 qf1 = *(const bf16x8*)(qptr + 32 + g * 8);

  f32x4 accO[4];
  #pragma unroll
  for (int dt = 0; dt < 4; ++dt) accO[dt] = (f32x4){0.f, 0.f, 0.f, 0.f};
  float mrun[4] = {-1e30f, -1e30f, -1e30f, -1e30f};
  float lrun[4] = {0.f, 0.f, 0.f, 0.f};

  const float scale = 0.03125f;                 // D^-0.5 (reference scales by n_embd)
  const int qout0 = qt * 64 + w * 16 + 4 * g;

  unsigned short* pb = &Pb[w][0];
  const int nsteps = qt + 1;

  for (int st = 0; st < nsteps; ++st) {
    const int s0 = st * 64;
    __syncthreads();
    #pragma unroll
    for (int r = 0; r < 2; ++r) {
      int c = tid + 256 * r;
      int srow = c >> 3, u = c & 7;
      GLOAD_LDS16(kbase + (size_t)(s0 + srow) * HDn + ((u ^ (srow & 7)) * 8), &Ks[c * 8]);
    }
    #pragma unroll
    for (int r = 0; r < 2; ++r) {
      int c = tid + 256 * r;
      int d = c >> 3, u = c & 7;
      GLOAD_LDS16(vbase + (size_t)d * Tn + s0 + ((u ^ (d & 7)) * 8), &Vs[c * 8]);
    }
    __syncthreads();

    float p[4][4];
    #pragma unroll
    for (int sub = 0; sub < 4; ++sub) {
      int srow = sub * 16 + (lane & 15);
      const char* kr = (const char*)Ks + srow * 128;
      bf16x8 kf0 = *(const bf16x8*)(kr + ((g ^ (srow & 7)) * 16));
      bf16x8 kf1 = *(const bf16x8*)(kr + (((4 + g) ^ (srow & 7)) * 16));
      f32x4 s4 = (f32x4){0.f, 0.f, 0.f, 0.f};
      s4 = __builtin_amdgcn_mfma_f32_16x16x32_bf16(qf0, kf0, s4, 0, 0, 0);
      s4 = __builtin_amdgcn_mfma_f32_16x16x32_bf16(qf1, kf1, s4, 0, 0, 0);
      int sg = s0 + srow;
      #pragma unroll
      for (int i = 0; i < 4; ++i)
        p[sub][i] = (sg > qout0 + i) ? -1e30f : s4[i] * scale;
    }

    #pragma unroll
    for (int i = 0; i < 4; ++i) {
      float v = fmaxf(fmaxf(p[0][i], p[1][i]), fmaxf(p[2][i], p[3][i]));
      v = fmaxf(v, __shfl_xor(v, 1)); v = fmaxf(v, __shfl_xor(v, 2));
      v = fmaxf(v, __shfl_xor(v, 4)); v = fmaxf(v, __shfl_xor(v, 8));
      float nm = fmaxf(mrun[i], v);
      float fac = __expf(mrun[i] - nm);
      mrun[i] = nm;
      #pragma unroll
      for (int dt = 0; dt < 4; ++dt) accO[dt][i] *= fac;
      float sum = 0.f;
      #pragma unroll
      for (int sub = 0; sub < 4; ++sub) {
        float e = __expf(p[sub][i] - nm);
        p[sub][i] = e;
        sum += e;
      }
      sum += __shfl_xor(sum, 1); sum += __shfl_xor(sum, 2);
      sum += __shfl_xor(sum, 4); sum += __shfl_xor(sum, 8);
      lrun[i] = lrun[i] * fac + sum;
    }

    #pragma unroll
    for (int sub = 0; sub < 4; ++sub) {
      int s = sub * 16 + (lane & 15);
      #pragma unroll
      for (int i = 0; i < 4; ++i) {
        int q = 4 * g + i;
        pb[q * 64 + (((s >> 3) ^ (q & 7)) * 8) + (s & 7)] = f2b(p[sub][i]);
      }
    }

    #pragma unroll
    for (int sc = 0; sc < 2; ++sc) {
      int qq = lane & 15;
      bf16x8 pa = *(const bf16x8*)((const char*)pb + qq * 128 + (((sc * 4 + g) ^ (qq & 7)) * 16));
      #pragma unroll
      for (int dt = 0; dt < 4; ++dt) {
        int d = dt * 16 + (lane & 15);
        bf16x8 vf = *(const bf16x8*)((const char*)Vs + d * 128 + (((sc * 4 + g) ^ (d & 7)) * 16));
        accO[dt] = __builtin_amdgcn_mfma_f32_16x16x32_bf16(pa, vf, accO[dt], 0, 0, 0);
      }
    }
  }

  float rinv[4];
  #pragma unroll
  for (int i = 0; i < 4; ++i) rinv[i] = 1.0f / lrun[i];
  #pragma unroll
  for (int dt = 0; dt < 4; ++dt) {
    int dcol = h * 64 + dt * 16 + (lane & 15);
    #pragma unroll
    for (int i = 0; i < 4; ++i) {
      int t = qout0 + i;
      ob[((size_t)(b * Tn + t)) * Dn + dcol] = f2b(accO[dt][i] * rinv[i]);
    }
  }
}

// ---------------- final loss: nll from gathered target logit + rowsum ------
__global__ __launch_bounds__(256) void loss_kernel(
    const float* __restrict__ logits, const float* __restrict__ rowsum,
    const int* __restrict__ target, float* __restrict__ out_loss) {
  __shared__ float red[4];
  int lane = threadIdx.x & 63, w = threadIdx.x >> 6;
  float s = 0.f;
  for (int row = threadIdx.x; row < NT; row += 256) {
    float lt = logits[(size_t)row * Vn + target[row]];
    s += logf(rowsum[row]) - lt;          // -(lt - log(sum))
  }
  #pragma unroll
  for (int off = 32; off > 0; off >>= 1) s += __shfl_down(s, off, 64);
  if (lane == 0) red[w] = s;
  __syncthreads();
  if (threadIdx.x == 0)
    *out_loss = (red[0] + red[1] + red[2] + red[3]) * (1.0f / NT);
}

// ---------------------------------------------------------------------------
static inline void launch_wcast(const float* src, unsigned short* dst, int K, int M,
                                long long bsk, long long bsh, hipStream_t s) {
  dim3 g(M >> 5, K >> 5);
  wcast_kernel<<<g, 256, 0, s>>>(src, dst, K, M, bsk, bsh);
}

template<int OMODE>
static inline void launch_mm(const unsigned short* A, const unsigned short* BT,
                             const float* bias, const float* res,
                             float* Cf, unsigned short* Ch, float* rowsum,
                             int N, int K, int M, int relu, hipStream_t s) {
  dim3 g(N >> 7, M >> 7);          // n fast, m slow: B-panel temporal locality
  mm_bf16<OMODE><<<g, 256, 0, s>>>(A, BT, bias, res, Cf, Ch, rowsum, N, K, M, relu);
}

extern "C" void kernel_launch(void* const* d_in, const int* in_sizes, int n_in,
                              void* d_out, int out_size, void* d_ws, size_t ws_size,
                              hipStream_t stream) {
  const int*   idx    = (const int*)d_in[0];
  const int*   target = (const int*)d_in[1];
  const float* tok    = (const float*)d_in[2];
  const float* pos    = (const float*)d_in[3];
  const float* wq     = (const float*)d_in[4];
  const float* wk     = (const float*)d_in[5];
  const float* wv     = (const float*)d_in[6];
  const float* wproj  = (const float*)d_in[7];
  const float* bproj  = (const float*)d_in[8];
  const float* ln1g   = (const float*)d_in[9];
  const float* ln1b   = (const float*)d_in[10];
  const float* ln2g   = (const float*)d_in[11];
  const float* ln2b   = (const float*)d_in[12];
  const float* w1     = (const float*)d_in[13];
  const float* b1     = (const float*)d_in[14];
  const float* w2     = (const float*)d_in[15];
  const float* b2     = (const float*)d_in[16];
  const float* lnfg   = (const float*)d_in[17];
  const float* lnfb   = (const float*)d_in[18];
  const float* wlm    = (const float*)d_in[19];
  const float* blm    = (const float*)d_in[20];

  float* out = (float*)d_out;          // logits [4096,32000] + loss scalar

  char* p = (char*)d_ws;
  float* x  = (float*)p;                 p += (size_t)NT * Dn * 4;
  unsigned short* xn = (unsigned short*)p; p += (size_t)NT * Dn * 2;
  unsigned short* reg = (unsigned short*)p; p += (size_t)NT * 4 * Dn * 2;
  unsigned short* wT = (unsigned short*)p; p += (size_t)Vn * Dn * 2;
  float* rowsum = (float*)p;

  unsigned short* qb  = reg;                         // [B][H][T][64]
  unsigned short* kb  = reg + (size_t)NT * Dn;       // [B][H][T][64]
  unsigned short* vtb = reg + 2 * (size_t)NT * Dn;   // [B][H][64][T]
  unsigned short* ob  = reg + 3 * (size_t)NT * Dn;   // [NT][D]
  unsigned short* hb  = reg;                         // MLP hidden, disjoint in time

  embed_kernel<<<NT, 256, 0, stream>>>(idx, tok, pos, x);

  for (int l = 0; l < Ln; ++l) {
    const float* wq_l = wq + (size_t)l * Hn * Dn * HDn;
    const float* wk_l = wk + (size_t)l * Hn * Dn * HDn;
    const float* wv_l = wv + (size_t)l * Hn * Dn * HDn;

    ln_kernel<<<NT, 256, 0, stream>>>(x, ln1g + l * Dn, ln1b + l * Dn, xn);

    // fused QKV: wT rows [0,1024)=q, [1024,2048)=k, [2048,3072)=v
    launch_wcast(wq_l, wT,                  Dn, Dn, HDn, (long long)Dn * HDn, stream);
    launch_wcast(wk_l, wT + 1024 * Dn,      Dn, Dn, HDn, (long long)Dn * HDn, stream);
    launch_wcast(wv_l, wT + 2048 * Dn,      Dn, Dn, HDn, (long long)Dn * HDn, stream);
    launch_mm<3>(xn, wT, nullptr, nullptr, nullptr, qb, nullptr, NT, Dn, 3072, 0, stream);

    fattn_kernel<<<Bn * Hn * (Tn / 64), 256, 0, stream>>>(qb, kb, vtb, ob);

    launch_wcast(wproj + (size_t)l * Dn * Dn, wT, Dn, Dn, Dn, 64, stream);
    launch_mm<0>(ob, wT, bproj + l * Dn, x, x, nullptr, nullptr, NT, Dn, Dn, 0, stream);

    ln_kernel<<<NT, 256, 0, stream>>>(x, ln2g + l * Dn, ln2b + l * Dn, xn);

    launch_wcast(w1 + (size_t)l * Dn * 4 * Dn, wT, Dn, 4 * Dn, 4 * Dn, 64, stream);
    launch_mm<0>(xn, wT, b1 + l * 4 * Dn, nullptr, nullptr, hb, nullptr, NT, Dn, 4 * Dn, 1, stream);
    launch_wcast(w2 + (size_t)l * 4 * Dn * Dn, wT, 4 * Dn, Dn, Dn, 64, stream);
    launch_mm<0>(hb, wT, b2 + l * Dn, x, x, nullptr, nullptr, NT, 4 * Dn, Dn, 0, stream);
  }

  ln_kernel<<<NT, 256, 0, stream>>>(x, lnfg, lnfb, xn);

  // logits + fused per-row exp-sums
  hipMemsetAsync(rowsum, 0, NT * sizeof(float), stream);
  launch_wcast(wlm, wT, Dn, Vn, Vn, 64, stream);
  launch_mm<4>(xn, wT, blm, nullptr, out, nullptr, rowsum, NT, Dn, Vn, 0, stream);

  loss_kernel<<<1, 256, 0, stream>>>(out, rowsum, target, out + (size_t)NT * Vn);
}

// Round 6
// 1428.310 us; speedup vs baseline: 9.4493x; 1.0577x over previous
//
#include <hip/hip_runtime.h>
#include <math.h>

// Problem constants
#define Dn   1024
#define Hn   16
#define HDn  64
#define Tn   1024
#define Bn   4
#define Vn   32000
#define Ln   3
#define NT   (Bn*Tn)        // 4096 token rows

typedef __attribute__((ext_vector_type(8))) short bf16x8;
typedef __attribute__((ext_vector_type(4))) float f32x4;
typedef __attribute__((ext_vector_type(8))) unsigned short u16x8;

__device__ __forceinline__ float b2f(unsigned short u) {
  union { float f; unsigned int i; } c; c.i = ((unsigned int)u) << 16; return c.f;
}
__device__ __forceinline__ unsigned short f2b(float f) {
  union { float f; unsigned int i; } c; c.f = f;
  unsigned int r = (c.i + 0x7FFFu + ((c.i >> 16) & 1u)) >> 16;
  return (unsigned short)r;
}

#define GLOAD_LDS16(g, l) __builtin_amdgcn_global_load_lds( \
    (const __attribute__((address_space(1))) void*)(g),     \
    (__attribute__((address_space(3))) void*)(l), 16, 0, 0)

// ---------------- embedding: x = tok_emb[idx] + pos_emb[t] (fp32) ----------
__global__ __launch_bounds__(256) void embed_kernel(
    const int* __restrict__ idx, const float* __restrict__ tok,
    const float* __restrict__ pos, float* __restrict__ x) {
  int row = blockIdx.x;
  int t = row & (Tn - 1);
  int token = idx[row];
  const float4* tp = (const float4*)(tok + (size_t)token * Dn);
  const float4* pp = (const float4*)(pos + (size_t)t * Dn);
  float4* xp = (float4*)(x + (size_t)row * Dn);
  int i = threadIdx.x;
  float4 a = tp[i], b = pp[i];
  xp[i] = make_float4(a.x + b.x, a.y + b.y, a.z + b.z, a.w + b.w);
}

// ---------------- LayerNorm: fp32 in, bf16 out -----------------------------
__global__ __launch_bounds__(256) void ln_kernel(
    const float* __restrict__ x, const float* __restrict__ g,
    const float* __restrict__ b, unsigned short* __restrict__ y) {
  int row = blockIdx.x;
  const float4* xr = (const float4*)(x + (size_t)row * Dn);
  __shared__ float red[4];
  int lane = threadIdx.x & 63, w = threadIdx.x >> 6;

  float4 v = xr[threadIdx.x];
  float s = v.x + v.y + v.z + v.w;
  #pragma unroll
  for (int o = 32; o > 0; o >>= 1) s += __shfl_down(s, o, 64);
  if (lane == 0) red[w] = s;
  __syncthreads();
  float mu = (red[0] + red[1] + red[2] + red[3]) * (1.0f / Dn);
  __syncthreads();

  float dx = v.x - mu, dy = v.y - mu, dz = v.z - mu, dw = v.w - mu;
  float ss = dx*dx + dy*dy + dz*dz + dw*dw;
  #pragma unroll
  for (int o = 32; o > 0; o >>= 1) ss += __shfl_down(ss, o, 64);
  if (lane == 0) red[w] = ss;
  __syncthreads();
  float var = (red[0] + red[1] + red[2] + red[3]) * (1.0f / Dn);
  float inv = rsqrtf(var + 1e-5f);

  float4 gv = ((const float4*)g)[threadIdx.x];
  float4 bv = ((const float4*)b)[threadIdx.x];
  ushort4 o4;
  o4.x = f2b(dx*inv*gv.x + bv.x);
  o4.y = f2b(dy*inv*gv.y + bv.y);
  o4.z = f2b(dz*inv*gv.z + bv.z);
  o4.w = f2b(dw*inv*gv.w + bv.w);
  ((ushort4*)(y + (size_t)row * Dn))[threadIdx.x] = o4;
}

// ---------------- weight transpose-cast: fp32 B(k,m) -> bf16 BT[m][k] ------
__global__ __launch_bounds__(256) void wcast_kernel(
    const float* __restrict__ src, unsigned short* __restrict__ dst,
    int K, int M, long long bsk, long long bsh) {
  __shared__ float t[32][33];
  int m0 = blockIdx.x << 5, k0 = blockIdx.y << 5;
  int tid = threadIdx.x;
  int ml = tid & 31, kl = tid >> 5;
  #pragma unroll
  for (int p = 0; p < 4; ++p) {
    int k = k0 + kl + p * 8;
    int m = m0 + ml;
    t[ml][kl + p * 8] = src[(size_t)k * bsk + (size_t)(m >> 6) * bsh + (m & 63)];
  }
  __syncthreads();
  int kl2 = tid & 31, ml2 = tid >> 5;
  #pragma unroll
  for (int p = 0; p < 4; ++p) {
    int m = m0 + ml2 + p * 8;
    int k = k0 + kl2;
    dst[(size_t)m * K + k] = f2b(t[ml2 + p * 8][kl2]);
  }
}

// ---------------- bf16 MFMA GEMM (128x128 tile, BK=32, 4 waves) ------------
// Used where M is small (proj, mlp2). grid = (N/128, M/128), n fast.
__global__ __launch_bounds__(256) void mm_bf16(
    const unsigned short* __restrict__ A, const unsigned short* __restrict__ BT,
    const float* __restrict__ bias, const float* __restrict__ res,
    float* __restrict__ Cf, unsigned short* __restrict__ Ch,
    int N, int K, int M, int relu) {
  __shared__ __align__(16) unsigned short As[128 * 32];
  __shared__ __align__(16) unsigned short Bs[128 * 32];
  const int tid = threadIdx.x;
  const int lane = tid & 63, w = tid >> 6, g = lane >> 4;
  const int wr = w >> 1, wc = w & 1;
  const int n0 = blockIdx.x << 7, m0 = blockIdx.y << 7;

  f32x4 acc[4][4];
  #pragma unroll
  for (int i = 0; i < 4; ++i)
    #pragma unroll
    for (int j = 0; j < 4; ++j)
      acc[i][j] = (f32x4){0.f, 0.f, 0.f, 0.f};

  const int beta0 = w * 2048 + lane * 16;
  const int beta1 = beta0 + 1024;
  const int r0 = beta0 >> 6, u0 = (beta0 >> 4) & 3;
  const int r1 = beta1 >> 6, u1 = (beta1 >> 4) & 3;
  const int ks0 = u0 ^ ((r0 >> 1) & 3);
  const int ks1 = u1 ^ ((r1 >> 1) & 3);
  const unsigned short* a_g0 = A + (size_t)(n0 + r0) * K + ks0 * 8;
  const unsigned short* a_g1 = A + (size_t)(n0 + r1) * K + ks1 * 8;
  const unsigned short* b_g0 = BT + (size_t)(m0 + r0) * K + ks0 * 8;
  const unsigned short* b_g1 = BT + (size_t)(m0 + r1) * K + ks1 * 8;
  unsigned short* a_l0 = As + w * 1024;
  unsigned short* a_l1 = As + w * 1024 + 512;
  unsigned short* b_l0 = Bs + w * 1024;
  unsigned short* b_l1 = Bs + w * 1024 + 512;

  int a_off[4], b_off[4];
  #pragma unroll
  for (int f = 0; f < 4; ++f) {
    int row = wr * 64 + f * 16 + (lane & 15);
    a_off[f] = row * 64 + ((g ^ ((row >> 1) & 3)) << 4);
    int col = wc * 64 + f * 16 + (lane & 15);
    b_off[f] = col * 64 + ((g ^ ((col >> 1) & 3)) << 4);
  }

  for (int k0 = 0; k0 < K; k0 += 32) {
    __syncthreads();
    GLOAD_LDS16(a_g0 + k0, a_l0);
    GLOAD_LDS16(a_g1 + k0, a_l1);
    GLOAD_LDS16(b_g0 + k0, b_l0);
    GLOAD_LDS16(b_g1 + k0, b_l1);
    __syncthreads();

    bf16x8 af[4], bfr[4];
    #pragma unroll
    for (int f = 0; f < 4; ++f) {
      af[f]  = *(const bf16x8*)((const char*)As + a_off[f]);
      bfr[f] = *(const bf16x8*)((const char*)Bs + b_off[f]);
    }
    #pragma unroll
    for (int i = 0; i < 4; ++i)
      #pragma unroll
      for (int j = 0; j < 4; ++j)
        acc[i][j] = __builtin_amdgcn_mfma_f32_16x16x32_bf16(af[i], bfr[j], acc[i][j], 0, 0, 0);
  }

  #pragma unroll
  for (int fc = 0; fc < 4; ++fc) {
    int colg = m0 + wc * 64 + fc * 16 + (lane & 15);
    float bz = bias ? bias[colg] : 0.f;
    #pragma unroll
    for (int fr = 0; fr < 4; ++fr) {
      #pragma unroll
      for (int i = 0; i < 4; ++i) {
        int rowg = n0 + wr * 64 + fr * 16 + (g << 2) + i;
        float v = acc[fr][fc][i] + bz;
        if (res) v += res[(size_t)rowg * M + colg];
        if (relu) v = fmaxf(v, 0.f);
        if (Cf) Cf[(size_t)rowg * M + colg] = v;
        else    Ch[(size_t)rowg * M + colg] = f2b(v);
      }
    }
  }
}

// ---------------- bf16 MFMA GEMM (128x256 tile, BK=32, 8 waves) ------------
// 512 threads, waves 2(M-rows)x4(N-cols), per-wave 64x64, same fragment math
// and LDS swizzle as mm_bf16. grid = (N/128, M/256), n fast.
// OMODE 0: row-major out + bias/res/relu
// OMODE 3: fused QKV (M=3072)
// OMODE 4: LM head: fp32 out + bias + per-row sum(exp) atomicAdd
template<int OMODE>
__global__ __launch_bounds__(512) void mm512_bf16(
    const unsigned short* __restrict__ A, const unsigned short* __restrict__ BT,
    const float* __restrict__ bias, const float* __restrict__ res,
    float* __restrict__ Cf, unsigned short* __restrict__ Ch,
    float* __restrict__ rowsum, int N, int K, int M, int relu) {
  __shared__ __align__(16) unsigned short As[128 * 32];
  __shared__ __align__(16) unsigned short Bs[256 * 32];
  __shared__ float rsum2[OMODE == 4 ? 128 * 4 : 4];
  const int tid = threadIdx.x;
  const int lane = tid & 63, w = tid >> 6, g = lane >> 4;
  const int wr = w >> 2, wc = w & 3;
  const int n0 = blockIdx.x << 7, m0 = blockIdx.y << 8;

  f32x4 acc[4][4];
  #pragma unroll
  for (int i = 0; i < 4; ++i)
    #pragma unroll
    for (int j = 0; j < 4; ++j)
      acc[i][j] = (f32x4){0.f, 0.f, 0.f, 0.f};

  // staging maps (linear LDS dest, inverse-swizzled global src)
  const int arow = tid >> 2, au = tid & 3;
  const int aks = au ^ ((arow >> 1) & 3);
  const unsigned short* a_g = A + (size_t)(n0 + arow) * K + aks * 8;
  unsigned short* a_l = As + tid * 8;
  const int brow0 = tid >> 2,          bu0 = tid & 3;
  const int brow1 = (tid + 512) >> 2,  bu1 = tid & 3;
  const int bks0 = bu0 ^ ((brow0 >> 1) & 3);
  const int bks1 = bu1 ^ ((brow1 >> 1) & 3);
  const unsigned short* b_g0 = BT + (size_t)(m0 + brow0) * K + bks0 * 8;
  const unsigned short* b_g1 = BT + (size_t)(m0 + brow1) * K + bks1 * 8;
  unsigned short* b_l0 = Bs + tid * 8;
  unsigned short* b_l1 = Bs + (tid + 512) * 8;

  int a_off[4], b_off[4];
  #pragma unroll
  for (int f = 0; f < 4; ++f) {
    int row = wr * 64 + f * 16 + (lane & 15);
    a_off[f] = row * 64 + ((g ^ ((row >> 1) & 3)) << 4);
    int col = wc * 64 + f * 16 + (lane & 15);
    b_off[f] = col * 64 + ((g ^ ((col >> 1) & 3)) << 4);
  }

  for (int k0 = 0; k0 < K; k0 += 32) {
    __syncthreads();
    GLOAD_LDS16(a_g + k0, a_l);
    GLOAD_LDS16(b_g0 + k0, b_l0);
    GLOAD_LDS16(b_g1 + k0, b_l1);
    __syncthreads();

    bf16x8 af[4], bfr[4];
    #pragma unroll
    for (int f = 0; f < 4; ++f) {
      af[f]  = *(const bf16x8*)((const char*)As + a_off[f]);
      bfr[f] = *(const bf16x8*)((const char*)Bs + b_off[f]);
    }
    #pragma unroll
    for (int i = 0; i < 4; ++i)
      #pragma unroll
      for (int j = 0; j < 4; ++j)
        acc[i][j] = __builtin_amdgcn_mfma_f32_16x16x32_bf16(af[i], bfr[j], acc[i][j], 0, 0, 0);
  }

  if (OMODE == 0) {
    #pragma unroll
    for (int fc = 0; fc < 4; ++fc) {
      int colg = m0 + wc * 64 + fc * 16 + (lane & 15);
      float bz = bias ? bias[colg] : 0.f;
      #pragma unroll
      for (int fr = 0; fr < 4; ++fr) {
        #pragma unroll
        for (int i = 0; i < 4; ++i) {
          int rowg = n0 + wr * 64 + fr * 16 + (g << 2) + i;
          float v = acc[fr][fc][i] + bz;
          if (res) v += res[(size_t)rowg * M + colg];
          if (relu) v = fmaxf(v, 0.f);
          if (Cf) Cf[(size_t)rowg * M + colg] = v;
          else    Ch[(size_t)rowg * M + colg] = f2b(v);
        }
      }
    }
  } else if (OMODE == 3) {
    unsigned short* kb  = Ch + (size_t)NT * Dn;
    unsigned short* vtb = Ch + 2 * (size_t)NT * Dn;
    #pragma unroll
    for (int fc = 0; fc < 4; ++fc) {
      int colg = m0 + wc * 64 + fc * 16 + (lane & 15);
      int sel = colg >> 10, hh = (colg >> 6) & 15, e = colg & 63;
      #pragma unroll
      for (int fr = 0; fr < 4; ++fr) {
        int rowg0 = n0 + wr * 64 + fr * 16 + (g << 2);
        int b = rowg0 >> 10, t0 = rowg0 & 1023;
        if (sel == 2) {
          ushort4 pk;
          pk.x = f2b(acc[fr][fc][0]); pk.y = f2b(acc[fr][fc][1]);
          pk.z = f2b(acc[fr][fc][2]); pk.w = f2b(acc[fr][fc][3]);
          *(ushort4*)&vtb[(((size_t)(b * 16 + hh) * 64) + e) * 1024 + t0] = pk;
        } else {
          unsigned short* dst = (sel == 0) ? Ch : kb;
          #pragma unroll
          for (int i = 0; i < 4; ++i)
            dst[(((size_t)(b * 16 + hh) * 1024) + t0 + i) * 64 + e] = f2b(acc[fr][fc][i]);
        }
      }
    }
  } else {
    // OMODE 4: LM head. rsum2[rloc*4 + wc] unique per (wr,fr,g,i,wc).
    #pragma unroll
    for (int fr = 0; fr < 4; ++fr) {
      #pragma unroll
      for (int i = 0; i < 4; ++i) {
        int rloc = wr * 64 + fr * 16 + (g << 2) + i;
        int rowg = n0 + rloc;
        float es = 0.f;
        #pragma unroll
        for (int fc = 0; fc < 4; ++fc) {
          int colg = m0 + wc * 64 + fc * 16 + (lane & 15);
          float v = acc[fr][fc][i] + bias[colg];
          Cf[(size_t)rowg * M + colg] = v;
          es += __expf(v);
        }
        es += __shfl_xor(es, 1); es += __shfl_xor(es, 2);
        es += __shfl_xor(es, 4); es += __shfl_xor(es, 8);
        if ((lane & 15) == 0) rsum2[rloc * 4 + wc] = es;
      }
    }
    __syncthreads();
    if (tid < 128)
      atomicAdd(&rowsum[n0 + tid],
                rsum2[tid * 4 + 0] + rsum2[tid * 4 + 1] +
                rsum2[tid * 4 + 2] + rsum2[tid * 4 + 3]);
  }
}

// ---------------- MFMA flash attention ------------------------------------
// q,k: [B][H][T][64] bf16; vt: [B][H][64][T] bf16; out ob: [NT][D] bf16
__global__ __launch_bounds__(256) void fattn_kernel(
    const unsigned short* __restrict__ qg, const unsigned short* __restrict__ kg,
    const unsigned short* __restrict__ vtg, unsigned short* __restrict__ ob) {
  const int bid = blockIdx.x;
  const int qt = bid & 15, bh = bid >> 4;
  const int b = bh >> 4, h = bh & 15;
  const int tid = threadIdx.x, lane = tid & 63, w = tid >> 6, g = lane >> 4;

  __shared__ __align__(16) unsigned short Ks[64 * 64];
  __shared__ __align__(16) unsigned short Vs[64 * 64];
  __shared__ __align__(16) unsigned short Pb[4][16 * 64];

  const unsigned short* kbase = kg + (size_t)bh * Tn * HDn;
  const unsigned short* vbase = vtg + (size_t)bh * HDn * Tn;

  const int qrow = qt * 64 + w * 16 + (lane & 15);
  const unsigned short* qptr = qg + ((size_t)bh * Tn + qrow) * HDn;
  bf16x8 qf0 = *(const bf16x8*)(qptr + g * 8);
  bf16x8 qf1 = *(const bf16x8*)(qptr + 32 + g * 8);

  f32x4 accO[4];
  #pragma unroll
  for (int dt = 0; dt < 4; ++dt) accO[dt] = (f32x4){0.f, 0.f, 0.f, 0.f};
  float mrun[4] = {-1e30f, -1e30f, -1e30f, -1e30f};
  float lrun[4] = {0.f, 0.f, 0.f, 0.f};

  const float scale = 0.03125f;                 // D^-0.5 (reference scales by n_embd)
  const int qout0 = qt * 64 + w * 16 + 4 * g;

  unsigned short* pb = &Pb[w][0];
  const int nsteps = qt + 1;

  for (int st = 0; st < nsteps; ++st) {
    const int s0 = st * 64;
    __syncthreads();
    #pragma unroll
    for (int r = 0; r < 2; ++r) {
      int c = tid + 256 * r;
      int srow = c >> 3, u = c & 7;
      GLOAD_LDS16(kbase + (size_t)(s0 + srow) * HDn + ((u ^ (srow & 7)) * 8), &Ks[c * 8]);
    }
    #pragma unroll
    for (int r = 0; r < 2; ++r) {
      int c = tid + 256 * r;
      int d = c >> 3, u = c & 7;
      GLOAD_LDS16(vbase + (size_t)d * Tn + s0 + ((u ^ (d & 7)) * 8), &Vs[c * 8]);
    }
    __syncthreads();

    float p[4][4];
    #pragma unroll
    for (int sub = 0; sub < 4; ++sub) {
      int srow = sub * 16 + (lane & 15);
      const char* kr = (const char*)Ks + srow * 128;
      bf16x8 kf0 = *(const bf16x8*)(kr + ((g ^ (srow & 7)) * 16));
      bf16x8 kf1 = *(const bf16x8*)(kr + (((4 + g) ^ (srow & 7)) * 16));
      f32x4 s4 = (f32x4){0.f, 0.f, 0.f, 0.f};
      s4 = __builtin_amdgcn_mfma_f32_16x16x32_bf16(qf0, kf0, s4, 0, 0, 0);
      s4 = __builtin_amdgcn_mfma_f32_16x16x32_bf16(qf1, kf1, s4, 0, 0, 0);
      int sg = s0 + srow;
      #pragma unroll
      for (int i = 0; i < 4; ++i)
        p[sub][i] = (sg > qout0 + i) ? -1e30f : s4[i] * scale;
    }

    #pragma unroll
    for (int i = 0; i < 4; ++i) {
      float v = fmaxf(fmaxf(p[0][i], p[1][i]), fmaxf(p[2][i], p[3][i]));
      v = fmaxf(v, __shfl_xor(v, 1)); v = fmaxf(v, __shfl_xor(v, 2));
      v = fmaxf(v, __shfl_xor(v, 4)); v = fmaxf(v, __shfl_xor(v, 8));
      float nm = fmaxf(mrun[i], v);
      float fac = __expf(mrun[i] - nm);
      mrun[i] = nm;
      #pragma unroll
      for (int dt = 0; dt < 4; ++dt) accO[dt][i] *= fac;
      float sum = 0.f;
      #pragma unroll
      for (int sub = 0; sub < 4; ++sub) {
        float e = __expf(p[sub][i] - nm);
        p[sub][i] = e;
        sum += e;
      }
      sum += __shfl_xor(sum, 1); sum += __shfl_xor(sum, 2);
      sum += __shfl_xor(sum, 4); sum += __shfl_xor(sum, 8);
      lrun[i] = lrun[i] * fac + sum;
    }

    #pragma unroll
    for (int sub = 0; sub < 4; ++sub) {
      int s = sub * 16 + (lane & 15);
      #pragma unroll
      for (int i = 0; i < 4; ++i) {
        int q = 4 * g + i;
        pb[q * 64 + (((s >> 3) ^ (q & 7)) * 8) + (s & 7)] = f2b(p[sub][i]);
      }
    }

    #pragma unroll
    for (int sc = 0; sc < 2; ++sc) {
      int qq = lane & 15;
      bf16x8 pa = *(const bf16x8*)((const char*)pb + qq * 128 + (((sc * 4 + g) ^ (qq & 7)) * 16));
      #pragma unroll
      for (int dt = 0; dt < 4; ++dt) {
        int d = dt * 16 + (lane & 15);
        bf16x8 vf = *(const bf16x8*)((const char*)Vs + d * 128 + (((sc * 4 + g) ^ (d & 7)) * 16));
        accO[dt] = __builtin_amdgcn_mfma_f32_16x16x32_bf16(pa, vf, accO[dt], 0, 0, 0);
      }
    }
  }

  float rinv[4];
  #pragma unroll
  for (int i = 0; i < 4; ++i) rinv[i] = 1.0f / lrun[i];
  #pragma unroll
  for (int dt = 0; dt < 4; ++dt) {
    int dcol = h * 64 + dt * 16 + (lane & 15);
    #pragma unroll
    for (int i = 0; i < 4; ++i) {
      int t = qout0 + i;
      ob[((size_t)(b * Tn + t)) * Dn + dcol] = f2b(accO[dt][i] * rinv[i]);
    }
  }
}

// ---------------- final loss: nll from gathered target logit + rowsum ------
__global__ __launch_bounds__(256) void loss_kernel(
    const float* __restrict__ logits, const float* __restrict__ rowsum,
    const int* __restrict__ target, float* __restrict__ out_loss) {
  __shared__ float red[4];
  int lane = threadIdx.x & 63, w = threadIdx.x >> 6;
  float s = 0.f;
  for (int row = threadIdx.x; row < NT; row += 256) {
    float lt = logits[(size_t)row * Vn + target[row]];
    s += logf(rowsum[row]) - lt;          // -(lt - log(sum))
  }
  #pragma unroll
  for (int off = 32; off > 0; off >>= 1) s += __shfl_down(s, off, 64);
  if (lane == 0) red[w] = s;
  __syncthreads();
  if (threadIdx.x == 0)
    *out_loss = (red[0] + red[1] + red[2] + red[3]) * (1.0f / NT);
}

// ---------------------------------------------------------------------------
static inline void launch_wcast(const float* src, unsigned short* dst, int K, int M,
                                long long bsk, long long bsh, hipStream_t s) {
  dim3 g(M >> 5, K >> 5);
  wcast_kernel<<<g, 256, 0, s>>>(src, dst, K, M, bsk, bsh);
}

static inline void launch_mm(const unsigned short* A, const unsigned short* BT,
                             const float* bias, const float* res,
                             float* Cf, unsigned short* Ch,
                             int N, int K, int M, int relu, hipStream_t s) {
  dim3 g(N >> 7, M >> 7);          // n fast, m slow: B-panel temporal locality
  mm_bf16<<<g, 256, 0, s>>>(A, BT, bias, res, Cf, Ch, N, K, M, relu);
}

template<int OMODE>
static inline void launch_mm512(const unsigned short* A, const unsigned short* BT,
                                const float* bias, const float* res,
                                float* Cf, unsigned short* Ch, float* rowsum,
                                int N, int K, int M, int relu, hipStream_t s) {
  dim3 g(N >> 7, M >> 8);          // n fast, m slow
  mm512_bf16<OMODE><<<g, 512, 0, s>>>(A, BT, bias, res, Cf, Ch, rowsum, N, K, M, relu);
}

extern "C" void kernel_launch(void* const* d_in, const int* in_sizes, int n_in,
                              void* d_out, int out_size, void* d_ws, size_t ws_size,
                              hipStream_t stream) {
  const int*   idx    = (const int*)d_in[0];
  const int*   target = (const int*)d_in[1];
  const float* tok    = (const float*)d_in[2];
  const float* pos    = (const float*)d_in[3];
  const float* wq     = (const float*)d_in[4];
  const float* wk     = (const float*)d_in[5];
  const float* wv     = (const float*)d_in[6];
  const float* wproj  = (const float*)d_in[7];
  const float* bproj  = (const float*)d_in[8];
  const float* ln1g   = (const float*)d_in[9];
  const float* ln1b   = (const float*)d_in[10];
  const float* ln2g   = (const float*)d_in[11];
  const float* ln2b   = (const float*)d_in[12];
  const float* w1     = (const float*)d_in[13];
  const float* b1     = (const float*)d_in[14];
  const float* w2     = (const float*)d_in[15];
  const float* b2     = (const float*)d_in[16];
  const float* lnfg   = (const float*)d_in[17];
  const float* lnfb   = (const float*)d_in[18];
  const float* wlm    = (const float*)d_in[19];
  const float* blm    = (const float*)d_in[20];

  float* out = (float*)d_out;          // logits [4096,32000] + loss scalar

  char* p = (char*)d_ws;
  float* x  = (float*)p;                 p += (size_t)NT * Dn * 4;
  unsigned short* xn = (unsigned short*)p; p += (size_t)NT * Dn * 2;
  unsigned short* reg = (unsigned short*)p; p += (size_t)NT * 4 * Dn * 2;
  unsigned short* wT = (unsigned short*)p; p += (size_t)Vn * Dn * 2;
  float* rowsum = (float*)p;

  unsigned short* qb  = reg;                         // [B][H][T][64]
  unsigned short* kb  = reg + (size_t)NT * Dn;       // [B][H][T][64]
  unsigned short* vtb = reg + 2 * (size_t)NT * Dn;   // [B][H][64][T]
  unsigned short* ob  = reg + 3 * (size_t)NT * Dn;   // [NT][D]
  unsigned short* hb  = reg;                         // MLP hidden, disjoint in time

  embed_kernel<<<NT, 256, 0, stream>>>(idx, tok, pos, x);

  for (int l = 0; l < Ln; ++l) {
    const float* wq_l = wq + (size_t)l * Hn * Dn * HDn;
    const float* wk_l = wk + (size_t)l * Hn * Dn * HDn;
    const float* wv_l = wv + (size_t)l * Hn * Dn * HDn;

    ln_kernel<<<NT, 256, 0, stream>>>(x, ln1g + l * Dn, ln1b + l * Dn, xn);

    // fused QKV: wT rows [0,1024)=q, [1024,2048)=k, [2048,3072)=v
    launch_wcast(wq_l, wT,                  Dn, Dn, HDn, (long long)Dn * HDn, stream);
    launch_wcast(wk_l, wT + 1024 * Dn,      Dn, Dn, HDn, (long long)Dn * HDn, stream);
    launch_wcast(wv_l, wT + 2048 * Dn,      Dn, Dn, HDn, (long long)Dn * HDn, stream);
    launch_mm512<3>(xn, wT, nullptr, nullptr, nullptr, qb, nullptr, NT, Dn, 3072, 0, stream);

    fattn_kernel<<<Bn * Hn * (Tn / 64), 256, 0, stream>>>(qb, kb, vtb, ob);

    launch_wcast(wproj + (size_t)l * Dn * Dn, wT, Dn, Dn, Dn, 64, stream);
    launch_mm(ob, wT, bproj + l * Dn, x, x, nullptr, NT, Dn, Dn, 0, stream);

    ln_kernel<<<NT, 256, 0, stream>>>(x, ln2g + l * Dn, ln2b + l * Dn, xn);

    launch_wcast(w1 + (size_t)l * Dn * 4 * Dn, wT, Dn, 4 * Dn, 4 * Dn, 64, stream);
    launch_mm512<0>(xn, wT, b1 + l * 4 * Dn, nullptr, nullptr, hb, nullptr, NT, Dn, 4 * Dn, 1, stream);
    launch_wcast(w2 + (size_t)l * 4 * Dn * Dn, wT, 4 * Dn, Dn, Dn, 64, stream);
    launch_mm(hb, wT, b2 + l * Dn, x, x, nullptr, NT, 4 * Dn, Dn, 0, stream);
  }

  ln_kernel<<<NT, 256, 0, stream>>>(x, lnfg, lnfb, xn);

  // logits + fused per-row exp-sums
  hipMemsetAsync(rowsum, 0, NT * sizeof(float), stream);
  launch_wcast(wlm, wT, Dn, Vn, Vn, 64, stream);
  launch_mm512<4>(xn, wT, blm, nullptr, out, nullptr, rowsum, NT, Dn, Vn, 0, stream);

  loss_kernel<<<1, 256, 0, stream>>>(out, rowsum, target, out + (size_t)NT * Vn);
}

// Round 7
// 1274.727 us; speedup vs baseline: 10.5877x; 1.1205x over previous
//
#include <hip/hip_runtime.h>
#include <math.h>

// Problem constants
#define Dn   1024
#define Hn   16
#define HDn  64
#define Tn   1024
#define Bn   4
#define Vn   32000
#define Ln   3
#define NT   (Bn*Tn)        // 4096 token rows

typedef __attribute__((ext_vector_type(8))) short bf16x8;
typedef __attribute__((ext_vector_type(4))) float f32x4;

__device__ __forceinline__ float b2f(unsigned short u) {
  union { float f; unsigned int i; } c; c.i = ((unsigned int)u) << 16; return c.f;
}
__device__ __forceinline__ unsigned short f2b(float f) {
  union { float f; unsigned int i; } c; c.f = f;
  unsigned int r = (c.i + 0x7FFFu + ((c.i >> 16) & 1u)) >> 16;
  return (unsigned short)r;
}

#define GLOAD_LDS16(g, l) __builtin_amdgcn_global_load_lds( \
    (const __attribute__((address_space(1))) void*)(g),     \
    (__attribute__((address_space(3))) void*)(l), 16, 0, 0)

#define SBAR()  __builtin_amdgcn_s_barrier()
#define SCHED() __builtin_amdgcn_sched_barrier(0)

// ---------------- embedding: x = tok_emb[idx] + pos_emb[t] (fp32) ----------
__global__ __launch_bounds__(256) void embed_kernel(
    const int* __restrict__ idx, const float* __restrict__ tok,
    const float* __restrict__ pos, float* __restrict__ x) {
  int row = blockIdx.x;
  int t = row & (Tn - 1);
  int token = idx[row];
  const float4* tp = (const float4*)(tok + (size_t)token * Dn);
  const float4* pp = (const float4*)(pos + (size_t)t * Dn);
  float4* xp = (float4*)(x + (size_t)row * Dn);
  int i = threadIdx.x;
  float4 a = tp[i], b = pp[i];
  xp[i] = make_float4(a.x + b.x, a.y + b.y, a.z + b.z, a.w + b.w);
}

// ---------------- LayerNorm: fp32 in, bf16 out -----------------------------
__global__ __launch_bounds__(256) void ln_kernel(
    const float* __restrict__ x, const float* __restrict__ g,
    const float* __restrict__ b, unsigned short* __restrict__ y) {
  int row = blockIdx.x;
  const float4* xr = (const float4*)(x + (size_t)row * Dn);
  __shared__ float red[4];
  int lane = threadIdx.x & 63, w = threadIdx.x >> 6;

  float4 v = xr[threadIdx.x];
  float s = v.x + v.y + v.z + v.w;
  #pragma unroll
  for (int o = 32; o > 0; o >>= 1) s += __shfl_down(s, o, 64);
  if (lane == 0) red[w] = s;
  __syncthreads();
  float mu = (red[0] + red[1] + red[2] + red[3]) * (1.0f / Dn);
  __syncthreads();

  float dx = v.x - mu, dy = v.y - mu, dz = v.z - mu, dw = v.w - mu;
  float ss = dx*dx + dy*dy + dz*dz + dw*dw;
  #pragma unroll
  for (int o = 32; o > 0; o >>= 1) ss += __shfl_down(ss, o, 64);
  if (lane == 0) red[w] = ss;
  __syncthreads();
  float var = (red[0] + red[1] + red[2] + red[3]) * (1.0f / Dn);
  float inv = rsqrtf(var + 1e-5f);

  float4 gv = ((const float4*)g)[threadIdx.x];
  float4 bv = ((const float4*)b)[threadIdx.x];
  ushort4 o4;
  o4.x = f2b(dx*inv*gv.x + bv.x);
  o4.y = f2b(dy*inv*gv.y + bv.y);
  o4.z = f2b(dz*inv*gv.z + bv.z);
  o4.w = f2b(dw*inv*gv.w + bv.w);
  ((ushort4*)(y + (size_t)row * Dn))[threadIdx.x] = o4;
}

// ---------------- weight transpose-cast: fp32 B(k,m) -> bf16 BT[m][k] ------
__global__ __launch_bounds__(256) void wcast_kernel(
    const float* __restrict__ src, unsigned short* __restrict__ dst,
    int K, int M, long long bsk, long long bsh) {
  __shared__ float t[32][33];
  int m0 = blockIdx.x << 5, k0 = blockIdx.y << 5;
  int tid = threadIdx.x;
  int ml = tid & 31, kl = tid >> 5;
  #pragma unroll
  for (int p = 0; p < 4; ++p) {
    int k = k0 + kl + p * 8;
    int m = m0 + ml;
    t[ml][kl + p * 8] = src[(size_t)k * bsk + (size_t)(m >> 6) * bsh + (m & 63)];
  }
  __syncthreads();
  int kl2 = tid & 31, ml2 = tid >> 5;
  #pragma unroll
  for (int p = 0; p < 4; ++p) {
    int m = m0 + ml2 + p * 8;
    int k = k0 + kl2;
    dst[(size_t)m * K + k] = f2b(t[ml2 + p * 8][kl2]);
  }
}

// ---------------- bf16 MFMA GEMM (128x128, BK=32, 4 waves, dbuf+vmcnt) -----
// Used where M is small (proj, mlp2). grid = (N/128, M/128), n fast.
__global__ __launch_bounds__(256) void mm_bf16(
    const unsigned short* __restrict__ A, const unsigned short* __restrict__ BT,
    const float* __restrict__ bias, const float* __restrict__ res,
    float* __restrict__ Cf, unsigned short* __restrict__ Ch,
    int N, int K, int M, int relu) {
  __shared__ __align__(16) unsigned short As[2][128 * 32];
  __shared__ __align__(16) unsigned short Bs[2][128 * 32];
  const int tid = threadIdx.x;
  const int lane = tid & 63, w = tid >> 6, g = lane >> 4;
  const int wr = w >> 1, wc = w & 1;
  const int n0 = blockIdx.x << 7, m0 = blockIdx.y << 7;

  f32x4 acc[4][4];
  #pragma unroll
  for (int i = 0; i < 4; ++i)
    #pragma unroll
    for (int j = 0; j < 4; ++j)
      acc[i][j] = (f32x4){0.f, 0.f, 0.f, 0.f};

  const int beta0 = w * 2048 + lane * 16;
  const int beta1 = beta0 + 1024;
  const int r0 = beta0 >> 6, u0 = (beta0 >> 4) & 3;
  const int r1 = beta1 >> 6, u1 = (beta1 >> 4) & 3;
  const int ks0 = u0 ^ ((r0 >> 1) & 3);
  const int ks1 = u1 ^ ((r1 >> 1) & 3);
  const unsigned short* a_g0 = A + (size_t)(n0 + r0) * K + ks0 * 8;
  const unsigned short* a_g1 = A + (size_t)(n0 + r1) * K + ks1 * 8;
  const unsigned short* b_g0 = BT + (size_t)(m0 + r0) * K + ks0 * 8;
  const unsigned short* b_g1 = BT + (size_t)(m0 + r1) * K + ks1 * 8;

  int a_off[4], b_off[4];
  #pragma unroll
  for (int f = 0; f < 4; ++f) {
    int row = wr * 64 + f * 16 + (lane & 15);
    a_off[f] = row * 64 + ((g ^ ((row >> 1) & 3)) << 4);
    int col = wc * 64 + f * 16 + (lane & 15);
    b_off[f] = col * 64 + ((g ^ ((col >> 1) & 3)) << 4);
  }

#define MM_STAGE(buf, kk) do {                                   \
    GLOAD_LDS16(a_g0 + (kk), As[buf] + w * 1024);                \
    GLOAD_LDS16(a_g1 + (kk), As[buf] + w * 1024 + 512);          \
    GLOAD_LDS16(b_g0 + (kk), Bs[buf] + w * 1024);                \
    GLOAD_LDS16(b_g1 + (kk), Bs[buf] + w * 1024 + 512); } while (0)

#define MM_COMPUTE(buf) do {                                     \
    bf16x8 af[4], bfr[4];                                        \
    _Pragma("unroll")                                            \
    for (int f = 0; f < 4; ++f) {                                \
      af[f]  = *(const bf16x8*)((const char*)As[buf] + a_off[f]);\
      bfr[f] = *(const bf16x8*)((const char*)Bs[buf] + b_off[f]);\
    }                                                            \
    _Pragma("unroll")                                            \
    for (int i = 0; i < 4; ++i)                                  \
      _Pragma("unroll")                                          \
      for (int j = 0; j < 4; ++j)                                \
        acc[i][j] = __builtin_amdgcn_mfma_f32_16x16x32_bf16(af[i], bfr[j], acc[i][j], 0, 0, 0); } while (0)

  MM_STAGE(0, 0);
  int cur = 0;
  for (int k0 = 0; k0 < K - 32; k0 += 32) {
    MM_STAGE(cur ^ 1, k0 + 32);
    asm volatile("s_waitcnt vmcnt(4)" ::: "memory");
    SCHED(); SBAR(); SCHED();
    MM_COMPUTE(cur);
    SCHED(); SBAR(); SCHED();
    cur ^= 1;
  }
  asm volatile("s_waitcnt vmcnt(0)" ::: "memory");
  SCHED(); SBAR(); SCHED();
  MM_COMPUTE(cur);

  #pragma unroll
  for (int fc = 0; fc < 4; ++fc) {
    int colg = m0 + wc * 64 + fc * 16 + (lane & 15);
    float bz = bias ? bias[colg] : 0.f;
    #pragma unroll
    for (int fr = 0; fr < 4; ++fr) {
      #pragma unroll
      for (int i = 0; i < 4; ++i) {
        int rowg = n0 + wr * 64 + fr * 16 + (g << 2) + i;
        float v = acc[fr][fc][i] + bz;
        if (res) v += res[(size_t)rowg * M + colg];
        if (relu) v = fmaxf(v, 0.f);
        if (Cf) Cf[(size_t)rowg * M + colg] = v;
        else    Ch[(size_t)rowg * M + colg] = f2b(v);
      }
    }
  }
#undef MM_STAGE
#undef MM_COMPUTE
}

// ---------------- bf16 MFMA GEMM (128x256, BK=32, 8 waves, dbuf+vmcnt) -----
// 512 threads, waves 2(M)x4(N), per-wave 64x64. grid = (N/128, M/256), n fast.
// OMODE 0: row-major out + bias/res/relu
// OMODE 3: fused QKV (M=3072)
// OMODE 4: LM head: fp32 out (nontemporal) + bias + per-row sum(exp) atomicAdd
template<int OMODE>
__global__ __launch_bounds__(512) void mm512_bf16(
    const unsigned short* __restrict__ A, const unsigned short* __restrict__ BT,
    const float* __restrict__ bias, const float* __restrict__ res,
    float* __restrict__ Cf, unsigned short* __restrict__ Ch,
    float* __restrict__ rowsum, int N, int K, int M, int relu) {
  __shared__ __align__(16) unsigned short As[2][128 * 32];
  __shared__ __align__(16) unsigned short Bs[2][256 * 32];
  __shared__ float rsum2[OMODE == 4 ? 128 * 4 : 4];
  const int tid = threadIdx.x;
  const int lane = tid & 63, w = tid >> 6, g = lane >> 4;
  const int wr = w >> 2, wc = w & 3;
  const int n0 = blockIdx.x << 7, m0 = blockIdx.y << 8;

  f32x4 acc[4][4];
  #pragma unroll
  for (int i = 0; i < 4; ++i)
    #pragma unroll
    for (int j = 0; j < 4; ++j)
      acc[i][j] = (f32x4){0.f, 0.f, 0.f, 0.f};

  const int arow = tid >> 2, au = tid & 3;
  const int aks = au ^ ((arow >> 1) & 3);
  const unsigned short* a_g = A + (size_t)(n0 + arow) * K + aks * 8;
  const int brow1 = (tid + 512) >> 2;
  const int bks0 = au ^ ((arow >> 1) & 3);
  const int bks1 = au ^ ((brow1 >> 1) & 3);
  const unsigned short* b_g0 = BT + (size_t)(m0 + arow) * K + bks0 * 8;
  const unsigned short* b_g1 = BT + (size_t)(m0 + brow1) * K + bks1 * 8;

  int a_off[4], b_off[4];
  #pragma unroll
  for (int f = 0; f < 4; ++f) {
    int row = wr * 64 + f * 16 + (lane & 15);
    a_off[f] = row * 64 + ((g ^ ((row >> 1) & 3)) << 4);
    int col = wc * 64 + f * 16 + (lane & 15);
    b_off[f] = col * 64 + ((g ^ ((col >> 1) & 3)) << 4);
  }

#define MM5_STAGE(buf, kk) do {                                  \
    GLOAD_LDS16(a_g + (kk), As[buf] + tid * 8);                  \
    GLOAD_LDS16(b_g0 + (kk), Bs[buf] + tid * 8);                 \
    GLOAD_LDS16(b_g1 + (kk), Bs[buf] + (tid + 512) * 8); } while (0)

#define MM5_COMPUTE(buf) do {                                    \
    bf16x8 af[4], bfr[4];                                        \
    _Pragma("unroll")                                            \
    for (int f = 0; f < 4; ++f) {                                \
      af[f]  = *(const bf16x8*)((const char*)As[buf] + a_off[f]);\
      bfr[f] = *(const bf16x8*)((const char*)Bs[buf] + b_off[f]);\
    }                                                            \
    _Pragma("unroll")                                            \
    for (int i = 0; i < 4; ++i)                                  \
      _Pragma("unroll")                                          \
      for (int j = 0; j < 4; ++j)                                \
        acc[i][j] = __builtin_amdgcn_mfma_f32_16x16x32_bf16(af[i], bfr[j], acc[i][j], 0, 0, 0); } while (0)

  MM5_STAGE(0, 0);
  int cur = 0;
  for (int k0 = 0; k0 < K - 32; k0 += 32) {
    MM5_STAGE(cur ^ 1, k0 + 32);
    asm volatile("s_waitcnt vmcnt(3)" ::: "memory");
    SCHED(); SBAR(); SCHED();
    MM5_COMPUTE(cur);
    SCHED(); SBAR(); SCHED();
    cur ^= 1;
  }
  asm volatile("s_waitcnt vmcnt(0)" ::: "memory");
  SCHED(); SBAR(); SCHED();
  MM5_COMPUTE(cur);

  if (OMODE == 0) {
    #pragma unroll
    for (int fc = 0; fc < 4; ++fc) {
      int colg = m0 + wc * 64 + fc * 16 + (lane & 15);
      float bz = bias ? bias[colg] : 0.f;
      #pragma unroll
      for (int fr = 0; fr < 4; ++fr) {
        #pragma unroll
        for (int i = 0; i < 4; ++i) {
          int rowg = n0 + wr * 64 + fr * 16 + (g << 2) + i;
          float v = acc[fr][fc][i] + bz;
          if (res) v += res[(size_t)rowg * M + colg];
          if (relu) v = fmaxf(v, 0.f);
          if (Cf) Cf[(size_t)rowg * M + colg] = v;
          else    Ch[(size_t)rowg * M + colg] = f2b(v);
        }
      }
    }
  } else if (OMODE == 3) {
    unsigned short* kb  = Ch + (size_t)NT * Dn;
    unsigned short* vtb = Ch + 2 * (size_t)NT * Dn;
    #pragma unroll
    for (int fc = 0; fc < 4; ++fc) {
      int colg = m0 + wc * 64 + fc * 16 + (lane & 15);
      int sel = colg >> 10, hh = (colg >> 6) & 15, e = colg & 63;
      #pragma unroll
      for (int fr = 0; fr < 4; ++fr) {
        int rowg0 = n0 + wr * 64 + fr * 16 + (g << 2);
        int b = rowg0 >> 10, t0 = rowg0 & 1023;
        if (sel == 2) {
          ushort4 pk;
          pk.x = f2b(acc[fr][fc][0]); pk.y = f2b(acc[fr][fc][1]);
          pk.z = f2b(acc[fr][fc][2]); pk.w = f2b(acc[fr][fc][3]);
          *(ushort4*)&vtb[(((size_t)(b * 16 + hh) * 64) + e) * 1024 + t0] = pk;
        } else {
          unsigned short* dst = (sel == 0) ? Ch : kb;
          #pragma unroll
          for (int i = 0; i < 4; ++i)
            dst[(((size_t)(b * 16 + hh) * 1024) + t0 + i) * 64 + e] = f2b(acc[fr][fc][i]);
        }
      }
    }
  } else {
    // OMODE 4: LM head. Nontemporal logit stores keep A/B panels L3-resident.
    #pragma unroll
    for (int fr = 0; fr < 4; ++fr) {
      #pragma unroll
      for (int i = 0; i < 4; ++i) {
        int rloc = wr * 64 + fr * 16 + (g << 2) + i;
        int rowg = n0 + rloc;
        float es = 0.f;
        #pragma unroll
        for (int fc = 0; fc < 4; ++fc) {
          int colg = m0 + wc * 64 + fc * 16 + (lane & 15);
          float v = acc[fr][fc][i] + bias[colg];
          __builtin_nontemporal_store(v, &Cf[(size_t)rowg * M + colg]);
          es += __expf(v);
        }
        es += __shfl_xor(es, 1); es += __shfl_xor(es, 2);
        es += __shfl_xor(es, 4); es += __shfl_xor(es, 8);
        if ((lane & 15) == 0) rsum2[rloc * 4 + wc] = es;
      }
    }
    __syncthreads();
    if (tid < 128)
      atomicAdd(&rowsum[n0 + tid],
                rsum2[tid * 4 + 0] + rsum2[tid * 4 + 1] +
                rsum2[tid * 4 + 2] + rsum2[tid * 4 + 3]);
  }
#undef MM5_STAGE
#undef MM5_COMPUTE
}

// ---------------- MFMA flash attention (dbuf KV + vmcnt) -------------------
// q,k: [B][H][T][64] bf16; vt: [B][H][64][T] bf16; out ob: [NT][D] bf16
__global__ __launch_bounds__(256) void fattn_kernel(
    const unsigned short* __restrict__ qg, const unsigned short* __restrict__ kg,
    const unsigned short* __restrict__ vtg, unsigned short* __restrict__ ob) {
  const int bid = blockIdx.x;
  const int qt = bid & 15, bh = bid >> 4;
  const int b = bh >> 4, h = bh & 15;
  const int tid = threadIdx.x, lane = tid & 63, w = tid >> 6, g = lane >> 4;

  __shared__ __align__(16) unsigned short Ks[2][64 * 64];
  __shared__ __align__(16) unsigned short Vs[2][64 * 64];
  __shared__ __align__(16) unsigned short Pb[4][16 * 64];

  const unsigned short* kbase = kg + (size_t)bh * Tn * HDn;
  const unsigned short* vbase = vtg + (size_t)bh * HDn * Tn;

  const int qrow = qt * 64 + w * 16 + (lane & 15);
  const unsigned short* qptr = qg + ((size_t)bh * Tn + qrow) * HDn;
  bf16x8 qf0 = *(const bf16x8*)(qptr + g * 8);
  bf16x8 qf1 = *(const bf16x8*)(qptr + 32 + g * 8);

  f32x4 accO[4];
  #pragma unroll
  for (int dt = 0; dt < 4; ++dt) accO[dt] = (f32x4){0.f, 0.f, 0.f, 0.f};
  float mrun[4] = {-1e30f, -1e30f, -1e30f, -1e30f};
  float lrun[4] = {0.f, 0.f, 0.f, 0.f};

  const float scale = 0.03125f;                 // D^-0.5 (reference scales by n_embd)
  const int qout0 = qt * 64 + w * 16 + 4 * g;

  unsigned short* pb = &Pb[w][0];
  const int nsteps = qt + 1;

#define FA_STAGE(buf, s0_) do {                                              \
    _Pragma("unroll")                                                        \
    for (int r = 0; r < 2; ++r) {                                            \
      int c = tid + 256 * r;                                                 \
      int srow = c >> 3, u = c & 7;                                          \
      GLOAD_LDS16(kbase + (size_t)((s0_) + srow) * HDn + ((u ^ (srow & 7)) * 8), Ks[buf] + c * 8); \
    }                                                                        \
    _Pragma("unroll")                                                        \
    for (int r = 0; r < 2; ++r) {                                            \
      int c = tid + 256 * r;                                                 \
      int d = c >> 3, u = c & 7;                                             \
      GLOAD_LDS16(vbase + (size_t)d * Tn + (s0_) + ((u ^ (d & 7)) * 8), Vs[buf] + c * 8); \
    } } while (0)

  FA_STAGE(0, 0);
  int cur = 0;

  for (int st = 0; st < nsteps; ++st) {
    const int s0 = st * 64;
    if (st + 1 < nsteps) {
      FA_STAGE(cur ^ 1, s0 + 64);
      asm volatile("s_waitcnt vmcnt(4)" ::: "memory");
    } else {
      asm volatile("s_waitcnt vmcnt(0)" ::: "memory");
    }
    SCHED(); SBAR(); SCHED();

    float p[4][4];
    #pragma unroll
    for (int sub = 0; sub < 4; ++sub) {
      int srow = sub * 16 + (lane & 15);
      const char* kr = (const char*)Ks[cur] + srow * 128;
      bf16x8 kf0 = *(const bf16x8*)(kr + ((g ^ (srow & 7)) * 16));
      bf16x8 kf1 = *(const bf16x8*)(kr + (((4 + g) ^ (srow & 7)) * 16));
      f32x4 s4 = (f32x4){0.f, 0.f, 0.f, 0.f};
      s4 = __builtin_amdgcn_mfma_f32_16x16x32_bf16(qf0, kf0, s4, 0, 0, 0);
      s4 = __builtin_amdgcn_mfma_f32_16x16x32_bf16(qf1, kf1, s4, 0, 0, 0);
      int sg = s0 + srow;
      #pragma unroll
      for (int i = 0; i < 4; ++i)
        p[sub][i] = (sg > qout0 + i) ? -1e30f : s4[i] * scale;
    }

    #pragma unroll
    for (int i = 0; i < 4; ++i) {
      float v = fmaxf(fmaxf(p[0][i], p[1][i]), fmaxf(p[2][i], p[3][i]));
      v = fmaxf(v, __shfl_xor(v, 1)); v = fmaxf(v, __shfl_xor(v, 2));
      v = fmaxf(v, __shfl_xor(v, 4)); v = fmaxf(v, __shfl_xor(v, 8));
      float nm = fmaxf(mrun[i], v);
      float fac = __expf(mrun[i] - nm);
      mrun[i] = nm;
      #pragma unroll
      for (int dt = 0; dt < 4; ++dt) accO[dt][i] *= fac;
      float sum = 0.f;
      #pragma unroll
      for (int sub = 0; sub < 4; ++sub) {
        float e = __expf(p[sub][i] - nm);
        p[sub][i] = e;
        sum += e;
      }
      sum += __shfl_xor(sum, 1); sum += __shfl_xor(sum, 2);
      sum += __shfl_xor(sum, 4); sum += __shfl_xor(sum, 8);
      lrun[i] = lrun[i] * fac + sum;
    }

    #pragma unroll
    for (int sub = 0; sub < 4; ++sub) {
      int s = sub * 16 + (lane & 15);
      #pragma unroll
      for (int i = 0; i < 4; ++i) {
        int q = 4 * g + i;
        pb[q * 64 + (((s >> 3) ^ (q & 7)) * 8) + (s & 7)] = f2b(p[sub][i]);
      }
    }

    #pragma unroll
    for (int sc = 0; sc < 2; ++sc) {
      int qq = lane & 15;
      bf16x8 pa = *(const bf16x8*)((const char*)pb + qq * 128 + (((sc * 4 + g) ^ (qq & 7)) * 16));
      #pragma unroll
      for (int dt = 0; dt < 4; ++dt) {
        int d = dt * 16 + (lane & 15);
        bf16x8 vf = *(const bf16x8*)((const char*)Vs[cur] + d * 128 + (((sc * 4 + g) ^ (d & 7)) * 16));
        accO[dt] = __builtin_amdgcn_mfma_f32_16x16x32_bf16(pa, vf, accO[dt], 0, 0, 0);
      }
    }

    SCHED(); SBAR(); SCHED();
    cur ^= 1;
  }
#undef FA_STAGE

  float rinv[4];
  #pragma unroll
  for (int i = 0; i < 4; ++i) rinv[i] = 1.0f / lrun[i];
  #pragma unroll
  for (int dt = 0; dt < 4; ++dt) {
    int dcol = h * 64 + dt * 16 + (lane & 15);
    #pragma unroll
    for (int i = 0; i < 4; ++i) {
      int t = qout0 + i;
      ob[((size_t)(b * Tn + t)) * Dn + dcol] = f2b(accO[dt][i] * rinv[i]);
    }
  }
}

// ---------------- final loss: nll from gathered target logit + rowsum ------
__global__ __launch_bounds__(256) void loss_kernel(
    const float* __restrict__ logits, const float* __restrict__ rowsum,
    const int* __restrict__ target, float* __restrict__ out_loss) {
  __shared__ float red[4];
  int lane = threadIdx.x & 63, w = threadIdx.x >> 6;
  float s = 0.f;
  for (int row = threadIdx.x; row < NT; row += 256) {
    float lt = logits[(size_t)row * Vn + target[row]];
    s += logf(rowsum[row]) - lt;          // -(lt - log(sum))
  }
  #pragma unroll
  for (int off = 32; off > 0; off >>= 1) s += __shfl_down(s, off, 64);
  if (lane == 0) red[w] = s;
  __syncthreads();
  if (threadIdx.x == 0)
    *out_loss = (red[0] + red[1] + red[2] + red[3]) * (1.0f / NT);
}

// ---------------------------------------------------------------------------
static inline void launch_wcast(const float* src, unsigned short* dst, int K, int M,
                                long long bsk, long long bsh, hipStream_t s) {
  dim3 g(M >> 5, K >> 5);
  wcast_kernel<<<g, 256, 0, s>>>(src, dst, K, M, bsk, bsh);
}

static inline void launch_mm(const unsigned short* A, const unsigned short* BT,
                             const float* bias, const float* res,
                             float* Cf, unsigned short* Ch,
                             int N, int K, int M, int relu, hipStream_t s) {
  dim3 g(N >> 7, M >> 7);          // n fast, m slow: B-panel temporal locality
  mm_bf16<<<g, 256, 0, s>>>(A, BT, bias, res, Cf, Ch, N, K, M, relu);
}

template<int OMODE>
static inline void launch_mm512(const unsigned short* A, const unsigned short* BT,
                                const float* bias, const float* res,
                                float* Cf, unsigned short* Ch, float* rowsum,
                                int N, int K, int M, int relu, hipStream_t s) {
  dim3 g(N >> 7, M >> 8);          // n fast, m slow
  mm512_bf16<OMODE><<<g, 512, 0, s>>>(A, BT, bias, res, Cf, Ch, rowsum, N, K, M, relu);
}

extern "C" void kernel_launch(void* const* d_in, const int* in_sizes, int n_in,
                              void* d_out, int out_size, void* d_ws, size_t ws_size,
                              hipStream_t stream) {
  const int*   idx    = (const int*)d_in[0];
  const int*   target = (const int*)d_in[1];
  const float* tok    = (const float*)d_in[2];
  const float* pos    = (const float*)d_in[3];
  const float* wq     = (const float*)d_in[4];
  const float* wk     = (const float*)d_in[5];
  const float* wv     = (const float*)d_in[6];
  const float* wproj  = (const float*)d_in[7];
  const float* bproj  = (const float*)d_in[8];
  const float* ln1g   = (const float*)d_in[9];
  const float* ln1b   = (const float*)d_in[10];
  const float* ln2g   = (const float*)d_in[11];
  const float* ln2b   = (const float*)d_in[12];
  const float* w1     = (const float*)d_in[13];
  const float* b1     = (const float*)d_in[14];
  const float* w2     = (const float*)d_in[15];
  const float* b2     = (const float*)d_in[16];
  const float* lnfg   = (const float*)d_in[17];
  const float* lnfb   = (const float*)d_in[18];
  const float* wlm    = (const float*)d_in[19];
  const float* blm    = (const float*)d_in[20];

  float* out = (float*)d_out;          // logits [4096,32000] + loss scalar

  char* p = (char*)d_ws;
  float* x  = (float*)p;                 p += (size_t)NT * Dn * 4;
  unsigned short* xn = (unsigned short*)p; p += (size_t)NT * Dn * 2;
  unsigned short* reg = (unsigned short*)p; p += (size_t)NT * 4 * Dn * 2;
  unsigned short* wT = (unsigned short*)p; p += (size_t)Vn * Dn * 2;
  float* rowsum = (float*)p;

  unsigned short* qb  = reg;                         // [B][H][T][64]
  unsigned short* kb  = reg + (size_t)NT * Dn;       // [B][H][T][64]
  unsigned short* vtb = reg + 2 * (size_t)NT * Dn;   // [B][H][64][T]
  unsigned short* ob  = reg + 3 * (size_t)NT * Dn;   // [NT][D]
  unsigned short* hb  = reg;                         // MLP hidden, disjoint in time

  embed_kernel<<<NT, 256, 0, stream>>>(idx, tok, pos, x);

  for (int l = 0; l < Ln; ++l) {
    const float* wq_l = wq + (size_t)l * Hn * Dn * HDn;
    const float* wk_l = wk + (size_t)l * Hn * Dn * HDn;
    const float* wv_l = wv + (size_t)l * Hn * Dn * HDn;

    ln_kernel<<<NT, 256, 0, stream>>>(x, ln1g + l * Dn, ln1b + l * Dn, xn);

    // fused QKV: wT rows [0,1024)=q, [1024,2048)=k, [2048,3072)=v
    launch_wcast(wq_l, wT,                  Dn, Dn, HDn, (long long)Dn * HDn, stream);
    launch_wcast(wk_l, wT + 1024 * Dn,      Dn, Dn, HDn, (long long)Dn * HDn, stream);
    launch_wcast(wv_l, wT + 2048 * Dn,      Dn, Dn, HDn, (long long)Dn * HDn, stream);
    launch_mm512<3>(xn, wT, nullptr, nullptr, nullptr, qb, nullptr, NT, Dn, 3072, 0, stream);

    fattn_kernel<<<Bn * Hn * (Tn / 64), 256, 0, stream>>>(qb, kb, vtb, ob);

    launch_wcast(wproj + (size_t)l * Dn * Dn, wT, Dn, Dn, Dn, 64, stream);
    launch_mm(ob, wT, bproj + l * Dn, x, x, nullptr, NT, Dn, Dn, 0, stream);

    ln_kernel<<<NT, 256, 0, stream>>>(x, ln2g + l * Dn, ln2b + l * Dn, xn);

    launch_wcast(w1 + (size_t)l * Dn * 4 * Dn, wT, Dn, 4 * Dn, 4 * Dn, 64, stream);
    launch_mm512<0>(xn, wT, b1 + l * 4 * Dn, nullptr, nullptr, hb, nullptr, NT, Dn, 4 * Dn, 1, stream);
    launch_wcast(w2 + (size_t)l * 4 * Dn * Dn, wT, 4 * Dn, Dn, Dn, 64, stream);
    launch_mm(hb, wT, b2 + l * Dn, x, x, nullptr, NT, 4 * Dn, Dn, 0, stream);
  }

  ln_kernel<<<NT, 256, 0, stream>>>(x, lnfg, lnfb, xn);

  // logits + fused per-row exp-sums
  hipMemsetAsync(rowsum, 0, NT * sizeof(float), stream);
  launch_wcast(wlm, wT, Dn, Vn, Vn, 64, stream);
  launch_mm512<4>(xn, wT, blm, nullptr, out, nullptr, rowsum, NT, Dn, Vn, 0, stream);

  loss_kernel<<<1, 256, 0, stream>>>(out, rowsum, target, out + (size_t)NT * Vn);
}